// Round 1
// baseline (977.067 us; speedup 1.0000x reference)
//
#include <hip/hip_runtime.h>
#include <hip/hip_bf16.h>
#include <math.h>

// Problem constants
#define B_   4
#define C_   512
#define HH_  8          // heads
#define DH_  64         // head dim
#define N_   1024       // H*W
#define L_   77         // context length
#define CTXD_ 768
#define GROUPS_ 32

// ---------------------------------------------------------------------------
// interference table: interf[n][m] = 0.1 * cos(2*pi*dist/( |wl|*32 + 1e-6 ))
// ---------------------------------------------------------------------------
__global__ __launch_bounds__(256)
void interf_kernel(const float* __restrict__ wl, float* __restrict__ interf)
{
    int idx = blockIdx.x * 256 + threadIdx.x;   // 0 .. 1M-1
    int n = idx >> 10, m = idx & 1023;
    float y1 = (float)(n >> 5), x1 = (float)(n & 31);
    float y2 = (float)(m >> 5), x2 = (float)(m & 31);
    float dy = y1 - y2, dx = x1 - x2;
    float dist = sqrtf(dy * dy + dx * dx + 1e-8f);
    float denom = fabsf(wl[0]) * 32.0f + 1e-6f;
    float phase = 6.283185307179586f * dist / denom;
    interf[idx] = 0.1f * cosf(phase);
}

// ---------------------------------------------------------------------------
// GroupNorm: 32 groups, 16 ch/group, 1024 px/ch. One block per (group,batch).
// ---------------------------------------------------------------------------
__global__ __launch_bounds__(256)
void groupnorm_kernel(const float* __restrict__ x, const float* __restrict__ w,
                      const float* __restrict__ bsc, float* __restrict__ out)
{
    int g = blockIdx.x;     // 0..31
    int b = blockIdx.y;     // 0..3
    const float* xb = x + ((size_t)b * C_ + g * 16) * N_;
    float s = 0.f, ss = 0.f;
    for (int l = threadIdx.x; l < 16 * N_; l += 256) {
        float v = xb[l];
        s += v; ss += v * v;
    }
    for (int off = 32; off; off >>= 1) {
        s  += __shfl_down(s,  off);
        ss += __shfl_down(ss, off);
    }
    __shared__ float sred[8], ssred[8];
    int wid = threadIdx.x >> 6;
    if ((threadIdx.x & 63) == 0) { sred[wid] = s; ssred[wid] = ss; }
    __syncthreads();
    if (threadIdx.x == 0) {
        float S = 0.f, SS = 0.f;
        for (int i = 0; i < 4; ++i) { S += sred[i]; SS += ssred[i]; }
        float mu = S * (1.f / 16384.f);
        float var = SS * (1.f / 16384.f) - mu * mu;
        sred[4] = mu;
        ssred[4] = rsqrtf(var + 1e-5f);
    }
    __syncthreads();
    float mu = sred[4], rs = ssred[4];
    float* ob = out + ((size_t)b * C_ + g * 16) * N_;
    for (int l = threadIdx.x; l < 16 * N_; l += 256) {
        int c = g * 16 + (l >> 10);
        ob[l] = (xb[l] - mu) * rs * w[c] + bsc[c];
    }
}

// ---------------------------------------------------------------------------
// Tiled fp32 GEMM. out[b][m][j] = sum_k A[..] * W[k][j]
//   ATRANS=true : A[b] layout [K][M]  (read A[k*M+m])
//   ATRANS=false: A[b] layout [M][K]
//   TRES=false  : out[b][m][j] = acc                (plain store)
//   TRES=true   : out[b][j][m] = res[b][j][m] + acc + bias[j]  (transposed)
// BM=BN=64, BK=16, 256 threads, 4x4 microtile.
// ---------------------------------------------------------------------------
template<bool ATRANS, bool TRES>
__global__ __launch_bounds__(256)
void gemm_kernel(const float* __restrict__ A, const float* __restrict__ W,
                 const float* __restrict__ bias, const float* __restrict__ res,
                 float* __restrict__ out, int M, int K, int J)
{
    int b  = blockIdx.z;
    int m0 = blockIdx.y * 64;
    int j0 = blockIdx.x * 64;
    const float* Ab = A + (size_t)b * M * K;
    __shared__ float As[16][68];
    __shared__ float Ws[16][68];
    int tid = threadIdx.x;
    int ty = tid >> 4, tx = tid & 15;
    float acc[4][4];
#pragma unroll
    for (int i = 0; i < 4; ++i)
#pragma unroll
        for (int j = 0; j < 4; ++j) acc[i][j] = 0.f;

    for (int k0 = 0; k0 < K; k0 += 16) {
        if (ATRANS) {
            for (int l = tid; l < 16 * 64; l += 256) {
                int kk = l >> 6, mm = l & 63;
                int m = m0 + mm;
                As[kk][mm] = (m < M) ? Ab[(size_t)(k0 + kk) * M + m] : 0.f;
            }
        } else {
            int mm = tid >> 2, k4 = tid & 3;
            int m = m0 + mm;
            float4 a4;
            if (m < M) a4 = *(const float4*)&Ab[(size_t)m * K + k0 + k4 * 4];
            else       a4 = make_float4(0.f, 0.f, 0.f, 0.f);
            As[k4 * 4 + 0][mm] = a4.x;
            As[k4 * 4 + 1][mm] = a4.y;
            As[k4 * 4 + 2][mm] = a4.z;
            As[k4 * 4 + 3][mm] = a4.w;
        }
        for (int l = tid; l < 16 * 64; l += 256) {
            int kk = l >> 6, jj = l & 63;
            Ws[kk][jj] = W[(size_t)(k0 + kk) * J + j0 + jj];
        }
        __syncthreads();
#pragma unroll
        for (int kk = 0; kk < 16; ++kk) {
            float4 a4 = *(const float4*)&As[kk][ty * 4];
            float4 w4 = *(const float4*)&Ws[kk][tx * 4];
            float av[4] = {a4.x, a4.y, a4.z, a4.w};
            float wv[4] = {w4.x, w4.y, w4.z, w4.w};
#pragma unroll
            for (int i = 0; i < 4; ++i)
#pragma unroll
                for (int j = 0; j < 4; ++j)
                    acc[i][j] = fmaf(av[i], wv[j], acc[i][j]);
        }
        __syncthreads();
    }

    if (!TRES) {
#pragma unroll
        for (int i = 0; i < 4; ++i) {
            int m = m0 + ty * 4 + i;
            if (m < M) {
                float4 v = make_float4(acc[i][0], acc[i][1], acc[i][2], acc[i][3]);
                *(float4*)&out[((size_t)b * M + m) * J + j0 + tx * 4] = v;
            }
        }
    } else {
#pragma unroll
        for (int j = 0; j < 4; ++j) {
            int jj = j0 + tx * 4 + j;
            float bv = bias[jj];
#pragma unroll
            for (int i = 0; i < 4; ++i) {
                int m = m0 + ty * 4 + i;
                size_t idx = ((size_t)b * J + jj) * M + m;
                out[idx] = res[idx] + acc[i][j] + bv;
            }
        }
    }
}

// ---------------------------------------------------------------------------
// Fresnel attention (flash-style). One block = (b, head, 32-query tile).
// qkv layout: [b][n][1536], q at col 0, k at 512, v at 1024.
// ao output: [b][n][512] with col = head*64 + d.
// ---------------------------------------------------------------------------
__global__ __launch_bounds__(256)
void fresnel_attn_kernel(const float* __restrict__ qkv,
                         const float* __restrict__ interf,
                         float* __restrict__ ao)
{
    int qb = blockIdx.x;     // 0..31
    int hh = blockIdx.y;     // 0..7
    int b  = blockIdx.z;     // 0..3
    int n0 = qb * 32;
    const float* qkvb = qkv + (size_t)b * N_ * 1536;

    __shared__ float Qs[32][65];
    __shared__ float Ks[64][65];
    __shared__ float Vs[64][65];
    __shared__ float Ps[32][65];

    int tid = threadIdx.x;
    int tq = tid >> 5;    // 0..7 -> owns rows tq*4 .. tq*4+3
    int tm = tid & 31;    // 0..31

    for (int l = tid; l < 32 * 64; l += 256) {
        int q = l >> 6, d = l & 63;
        Qs[q][d] = qkvb[(size_t)(n0 + q) * 1536 + hh * 64 + d];
    }

    float mrun[4], lrun[4], o[4][2];
#pragma unroll
    for (int i = 0; i < 4; ++i) {
        mrun[i] = -1e30f; lrun[i] = 0.f; o[i][0] = 0.f; o[i][1] = 0.f;
    }
    const float scale = 0.125f;   // 64^-0.5

    for (int m0 = 0; m0 < N_; m0 += 64) {
        __syncthreads();   // previous phase2 done before restage
        for (int l = tid; l < 64 * 64; l += 256) {
            int m = l >> 6, d = l & 63;
            size_t base = (size_t)(m0 + m) * 1536 + hh * 64 + d;
            Ks[m][d] = qkvb[base + 512];
            Vs[m][d] = qkvb[base + 1024];
        }
        __syncthreads();

        // phase 1: S[q][m] for q = tq*4+i, m = tm + 32j
        float s[4][2];
#pragma unroll
        for (int i = 0; i < 4; ++i) { s[i][0] = 0.f; s[i][1] = 0.f; }
        for (int d = 0; d < 64; ++d) {
            float k0v = Ks[tm][d], k1v = Ks[tm + 32][d];
#pragma unroll
            for (int i = 0; i < 4; ++i) {
                float qv = Qs[tq * 4 + i][d];
                s[i][0] = fmaf(qv, k0v, s[i][0]);
                s[i][1] = fmaf(qv, k1v, s[i][1]);
            }
        }
#pragma unroll
        for (int i = 0; i < 4; ++i) {
            size_t qrow = (size_t)(n0 + tq * 4 + i) * N_ + m0;
            s[i][0] = fmaf(s[i][0], scale, interf[qrow + tm]);
            s[i][1] = fmaf(s[i][1], scale, interf[qrow + tm + 32]);
        }

        // online softmax (per-row over half-wave)
#pragma unroll
        for (int i = 0; i < 4; ++i) {
            float tmax = fmaxf(s[i][0], s[i][1]);
            for (int off = 1; off < 32; off <<= 1)
                tmax = fmaxf(tmax, __shfl_xor(tmax, off));
            float mnew = fmaxf(mrun[i], tmax);
            float p0 = expf(s[i][0] - mnew);
            float p1 = expf(s[i][1] - mnew);
            float tsum = p0 + p1;
            for (int off = 1; off < 32; off <<= 1)
                tsum += __shfl_xor(tsum, off);
            float r = expf(mrun[i] - mnew);
            lrun[i] = lrun[i] * r + tsum;
            mrun[i] = mnew;
            o[i][0] *= r; o[i][1] *= r;
            Ps[tq * 4 + i][tm] = p0;
            Ps[tq * 4 + i][tm + 32] = p1;
        }
        __syncthreads();

        // phase 2: O += P @ V   (thread owns d = tm, tm+32)
        for (int m = 0; m < 64; ++m) {
            float v0 = Vs[m][tm], v1 = Vs[m][tm + 32];
#pragma unroll
            for (int i = 0; i < 4; ++i) {
                float p = Ps[tq * 4 + i][m];
                o[i][0] = fmaf(p, v0, o[i][0]);
                o[i][1] = fmaf(p, v1, o[i][1]);
            }
        }
    }

#pragma unroll
    for (int i = 0; i < 4; ++i) {
        float inv = 1.f / lrun[i];
        size_t base = ((size_t)b * N_ + n0 + tq * 4 + i) * 512 + hh * 64;
        ao[base + tm]      = o[i][0] * inv;
        ao[base + tm + 32] = o[i][1] * inv;
    }
}

// ---------------------------------------------------------------------------
// Cross attention: L=77 keys, single tile. One block = (b, head, 32 queries).
// q2: [b][1024][512], k2/v2: [b][77][512], ao2: [b][1024][512]
// ---------------------------------------------------------------------------
__global__ __launch_bounds__(256)
void cross_attn_kernel(const float* __restrict__ q2, const float* __restrict__ k2,
                       const float* __restrict__ v2, float* __restrict__ ao2)
{
    int qb = blockIdx.x, hh = blockIdx.y, b = blockIdx.z;
    int n0 = qb * 32;
    __shared__ float Qs[32][65];
    __shared__ float Ks[77][65];
    __shared__ float Vs[77][65];
    __shared__ float Ps[32][80];

    int tid = threadIdx.x;
    int tq = tid >> 5, tm = tid & 31;

    for (int l = tid; l < 32 * 64; l += 256) {
        int q = l >> 6, d = l & 63;
        Qs[q][d] = q2[((size_t)b * N_ + n0 + q) * 512 + hh * 64 + d];
    }
    for (int l = tid; l < L_ * 64; l += 256) {
        int m = l >> 6, d = l & 63;
        Ks[m][d] = k2[((size_t)b * L_ + m) * 512 + hh * 64 + d];
        Vs[m][d] = v2[((size_t)b * L_ + m) * 512 + hh * 64 + d];
    }
    __syncthreads();

    float s[4][3];
#pragma unroll
    for (int i = 0; i < 4; ++i) { s[i][0] = 0.f; s[i][1] = 0.f; s[i][2] = 0.f; }
    for (int d = 0; d < 64; ++d) {
        float k0v = Ks[tm][d];
        float k1v = Ks[tm + 32][d];
        float k2v = (tm < 13) ? Ks[tm + 64][d] : 0.f;
#pragma unroll
        for (int i = 0; i < 4; ++i) {
            float qv = Qs[tq * 4 + i][d];
            s[i][0] = fmaf(qv, k0v, s[i][0]);
            s[i][1] = fmaf(qv, k1v, s[i][1]);
            s[i][2] = fmaf(qv, k2v, s[i][2]);
        }
    }
    const float scale = 0.125f;
    float rsum[4];
#pragma unroll
    for (int i = 0; i < 4; ++i) {
        s[i][0] *= scale; s[i][1] *= scale; s[i][2] *= scale;
        float mx = fmaxf(s[i][0], s[i][1]);
        if (tm < 13) mx = fmaxf(mx, s[i][2]);
        for (int off = 1; off < 32; off <<= 1)
            mx = fmaxf(mx, __shfl_xor(mx, off));
        float p0 = expf(s[i][0] - mx);
        float p1 = expf(s[i][1] - mx);
        float p2 = (tm < 13) ? expf(s[i][2] - mx) : 0.f;
        float sum = p0 + p1 + p2;
        for (int off = 1; off < 32; off <<= 1)
            sum += __shfl_xor(sum, off);
        Ps[tq * 4 + i][tm] = p0;
        Ps[tq * 4 + i][tm + 32] = p1;
        if (tm < 13) Ps[tq * 4 + i][tm + 64] = p2;
        rsum[i] = 1.f / sum;
    }
    __syncthreads();

    float o[4][2];
#pragma unroll
    for (int i = 0; i < 4; ++i) { o[i][0] = 0.f; o[i][1] = 0.f; }
    for (int m = 0; m < L_; ++m) {
        float v0 = Vs[m][tm], v1 = Vs[m][tm + 32];
#pragma unroll
        for (int i = 0; i < 4; ++i) {
            float p = Ps[tq * 4 + i][m];
            o[i][0] = fmaf(p, v0, o[i][0]);
            o[i][1] = fmaf(p, v1, o[i][1]);
        }
    }
#pragma unroll
    for (int i = 0; i < 4; ++i) {
        size_t base = ((size_t)b * N_ + n0 + tq * 4 + i) * 512 + hh * 64;
        ao2[base + tm]      = o[i][0] * rsum[i];
        ao2[base + tm + 32] = o[i][1] * rsum[i];
    }
}

// ---------------------------------------------------------------------------
extern "C" void kernel_launch(void* const* d_in, const int* in_sizes, int n_in,
                              void* d_out, int out_size, void* d_ws, size_t ws_size,
                              hipStream_t stream)
{
    const float* x    = (const float*)d_in[0];
    const float* ctx  = (const float*)d_in[1];
    const float* gn1w = (const float*)d_in[2];
    const float* gn1b = (const float*)d_in[3];
    const float* gn2w = (const float*)d_in[4];
    const float* gn2b = (const float*)d_in[5];
    const float* qkvw = (const float*)d_in[6];
    const float* faow = (const float*)d_in[7];
    const float* faob = (const float*)d_in[8];
    const float* wl   = (const float*)d_in[9];
    const float* caqw = (const float*)d_in[10];
    const float* cakw = (const float*)d_in[11];
    const float* cavw = (const float*)d_in[12];
    const float* caow = (const float*)d_in[13];
    const float* caob = (const float*)d_in[14];
    float* out = (float*)d_out;
    float* ws  = (float*)d_ws;

    const size_t M1 = 1 << 20;
    float* interf = ws;              // 1M floats
    float* h1     = ws + M1;         // 2M
    float* qkvb   = ws + 3 * M1;     // 6M
    float* ao     = ws + 9 * M1;     // 2M
    float* x1     = ws + 11 * M1;    // 2M
    // reuse after fresnel path is consumed:
    float* h2  = h1;
    float* q2  = qkvb;               // 2M
    float* k2  = qkvb + 2 * M1;      // 4*77*512 = 157,696 floats
    float* v2  = k2 + (size_t)B_ * L_ * 512;
    float* ao2 = ao;

    interf_kernel<<<4096, 256, 0, stream>>>(wl, interf);
    groupnorm_kernel<<<dim3(32, 4), 256, 0, stream>>>(x, gn1w, gn1b, h1);
    // qkv = h1^T @ qkv_w : M=1024, K=512, J=1536
    gemm_kernel<true, false><<<dim3(24, 16, 4), 256, 0, stream>>>(
        h1, qkvw, nullptr, nullptr, qkvb, 1024, 512, 1536);
    fresnel_attn_kernel<<<dim3(32, 8, 4), 256, 0, stream>>>(qkvb, interf, ao);
    // x1 = x + ao @ fa_out_w + fa_out_b  (transposed store to [b][c][n])
    gemm_kernel<false, true><<<dim3(8, 16, 4), 256, 0, stream>>>(
        ao, faow, faob, x, x1, 1024, 512, 512);
    groupnorm_kernel<<<dim3(32, 4), 256, 0, stream>>>(x1, gn2w, gn2b, h2);
    // q2 = h2^T @ ca_q_w : M=1024, K=512, J=512
    gemm_kernel<true, false><<<dim3(8, 16, 4), 256, 0, stream>>>(
        h2, caqw, nullptr, nullptr, q2, 1024, 512, 512);
    // k2/v2 = ctx @ ca_{k,v}_w : M=77, K=768, J=512
    gemm_kernel<false, false><<<dim3(8, 2, 4), 256, 0, stream>>>(
        ctx, cakw, nullptr, nullptr, k2, 77, 768, 512);
    gemm_kernel<false, false><<<dim3(8, 2, 4), 256, 0, stream>>>(
        ctx, cavw, nullptr, nullptr, v2, 77, 768, 512);
    cross_attn_kernel<<<dim3(32, 8, 4), 256, 0, stream>>>(q2, k2, v2, ao2);
    // out = x1 + ao2 @ ca_out_w + ca_out_b  (transposed store)
    gemm_kernel<false, true><<<dim3(8, 16, 4), 256, 0, stream>>>(
        ao2, caow, caob, x1, out, 1024, 512, 512);
}

// Round 2
// 336.302 us; speedup vs baseline: 2.9053x; 2.9053x over previous
//
#include <hip/hip_runtime.h>
#include <hip/hip_bf16.h>
#include <math.h>

#define B_    4
#define HH_   8
#define N_    1024
#define L_    77

typedef float f4 __attribute__((ext_vector_type(4)));
typedef short bf8 __attribute__((ext_vector_type(8)));
typedef short s4v __attribute__((ext_vector_type(4)));

__device__ __forceinline__ float fs(short s) {
    unsigned u = ((unsigned)(unsigned short)s) << 16;
    return __builtin_bit_cast(float, u);
}
__device__ __forceinline__ short sf(float f) {
    unsigned u = __builtin_bit_cast(unsigned, f);
    unsigned r = (u + 0x7FFF + ((u >> 16) & 1)) >> 16;
    return (short)r;
}
__device__ __forceinline__ bf8 zero8() { bf8 v; for (int i = 0; i < 8; ++i) v[i] = 0; return v; }
__device__ __forceinline__ f4 zerof4() { f4 v; for (int i = 0; i < 4; ++i) v[i] = 0.f; return v; }

#define MFMA(a, b, c) __builtin_amdgcn_mfma_f32_16x16x32_bf16((a), (b), (c), 0, 0, 0)

// ---------------------------------------------------------------------------
// interference table: tab[(dy+31)*63 + dx+31] = bf16( 0.1*cos(2*pi*dist/den) )
// ---------------------------------------------------------------------------
__global__ __launch_bounds__(256)
void tab_kernel(const float* __restrict__ wl, short* __restrict__ tab)
{
    int idx = blockIdx.x * 256 + threadIdx.x;
    if (idx < 3969) {
        int i = idx / 63, j = idx - i * 63;
        float dy = (float)(i - 31), dx = (float)(j - 31);
        float dist = sqrtf(dy * dy + dx * dx + 1e-8f);
        float den = fabsf(wl[0]) * 32.0f + 1e-6f;
        tab[idx] = sf(0.1f * cosf(6.283185307179586f * dist / den));
    }
}

// ---------------------------------------------------------------------------
// fp32 transpose per batch: in [R][C] -> out [C][R]
// ---------------------------------------------------------------------------
__global__ __launch_bounds__(256)
void transpose_f32(const float* __restrict__ in, float* __restrict__ out, int R, int C)
{
    __shared__ float t[32][33];
    int tx = threadIdx.x & 31, ty = threadIdx.x >> 5;
    int r0 = blockIdx.y * 32, c0 = blockIdx.x * 32;
    size_t bo = (size_t)blockIdx.z * R * C;
#pragma unroll
    for (int i = 0; i < 4; ++i)
        t[ty + i * 8][tx] = in[bo + (size_t)(r0 + ty + i * 8) * C + c0 + tx];
    __syncthreads();
#pragma unroll
    for (int i = 0; i < 4; ++i)
        out[bo + (size_t)(c0 + ty + i * 8) * R + r0 + tx] = t[tx][ty + i * 8];
}

// ---------------------------------------------------------------------------
// weight transpose+convert: in fp32 [K][J] -> out bf16 [J][K]
// ---------------------------------------------------------------------------
__global__ __launch_bounds__(256)
void wtrans_kernel(const float* __restrict__ in, short* __restrict__ out, int K, int J)
{
    __shared__ float t[32][33];
    int tx = threadIdx.x & 31, ty = threadIdx.x >> 5;
    int k0 = blockIdx.y * 32, j0 = blockIdx.x * 32;
#pragma unroll
    for (int i = 0; i < 4; ++i)
        t[ty + i * 8][tx] = in[(size_t)(k0 + ty + i * 8) * J + j0 + tx];
    __syncthreads();
#pragma unroll
    for (int i = 0; i < 4; ++i)
        out[(size_t)(j0 + ty + i * 8) * K + k0 + tx] = sf(t[tx][ty + i * 8]);
}

// ---------------------------------------------------------------------------
// GroupNorm over [n][c] layout, output bf16. One block per (group, batch).
// ---------------------------------------------------------------------------
__global__ __launch_bounds__(256)
void groupnorm_nc(const float* __restrict__ x, const float* __restrict__ w,
                  const float* __restrict__ bs, short* __restrict__ out)
{
    int g = blockIdx.x, b = blockIdx.y;
    const float* xb = x + (size_t)b * 524288 + g * 16;
    short* ob = out + (size_t)b * 524288 + g * 16;
    float s = 0.f, ss = 0.f;
    for (int l = threadIdx.x; l < 4096; l += 256) {
        int n = l >> 2, c4 = l & 3;
        float4 v = *(const float4*)(xb + (size_t)n * 512 + c4 * 4);
        s += v.x + v.y + v.z + v.w;
        ss += v.x * v.x + v.y * v.y + v.z * v.z + v.w * v.w;
    }
    for (int off = 32; off; off >>= 1) {
        s  += __shfl_down(s,  off);
        ss += __shfl_down(ss, off);
    }
    __shared__ float sred[8], ssred[8];
    int wid = threadIdx.x >> 6;
    if ((threadIdx.x & 63) == 0) { sred[wid] = s; ssred[wid] = ss; }
    __syncthreads();
    if (threadIdx.x == 0) {
        float S = 0.f, SS = 0.f;
        for (int i = 0; i < 4; ++i) { S += sred[i]; SS += ssred[i]; }
        float mu = S * (1.f / 16384.f);
        float var = SS * (1.f / 16384.f) - mu * mu;
        sred[4] = mu; ssred[4] = rsqrtf(var + 1e-5f);
    }
    __syncthreads();
    float mu = sred[4], rs = ssred[4];
    for (int l = threadIdx.x; l < 4096; l += 256) {
        int n = l >> 2, c4 = l & 3, c = g * 16 + c4 * 4;
        float4 v = *(const float4*)(xb + (size_t)n * 512 + c4 * 4);
        s4v o;
        o[0] = sf((v.x - mu) * rs * w[c + 0] + bs[c + 0]);
        o[1] = sf((v.y - mu) * rs * w[c + 1] + bs[c + 1]);
        o[2] = sf((v.z - mu) * rs * w[c + 2] + bs[c + 2]);
        o[3] = sf((v.w - mu) * rs * w[c + 3] + bs[c + 3]);
        *(s4v*)(ob + (size_t)n * 512 + c4 * 4) = o;
    }
}

// ---------------------------------------------------------------------------
// MFMA GEMM: out[b][m][j] = sum_k A[b][m][k] * Wt[j][k]   (Wt pre-transposed)
// 128x128 tile, 4 waves (2x2 of 64x64), K-step 32.
// AF32: A is fp32 (converted during staging). EPI 0: bf16 store.
// EPI 1: fp32 store with +bias[j] +res[b][m][j].
// ---------------------------------------------------------------------------
template<bool AF32, int EPI>
__global__ __launch_bounds__(256)
void gemm_mfma(const void* __restrict__ Av, const short* __restrict__ Wt,
               const float* __restrict__ bias, const float* __restrict__ res,
               void* __restrict__ outv, int M, int K, int J,
               long aStride, long oStride)
{
    int j0 = blockIdx.x * 128, m0 = blockIdx.y * 128, b = blockIdx.z;
    __shared__ short As[128][40];
    __shared__ short Ws[128][40];
    int tid = threadIdx.x, w = tid >> 6, lane = tid & 63;
    int lr = lane & 15, lg = lane >> 4;
    int wr = w >> 1, wc = w & 1;
    f4 acc[4][4];
#pragma unroll
    for (int i = 0; i < 4; ++i)
#pragma unroll
        for (int j = 0; j < 4; ++j) acc[i][j] = zerof4();

    for (int k0 = 0; k0 < K; k0 += 32) {
        __syncthreads();
#pragma unroll
        for (int it = 0; it < 2; ++it) {
            int sID = it * 256 + tid;
            int m = sID >> 2, kq = sID & 3;
            bf8 v;
            if (!AF32) {
                const short* A = (const short*)Av + (size_t)b * aStride;
                v = (m0 + m < M) ? *(const bf8*)(A + (size_t)(m0 + m) * K + k0 + kq * 8)
                                 : zero8();
            } else {
                const float* A = (const float*)Av + (size_t)b * aStride;
                if (m0 + m < M) {
                    float4 f0 = *(const float4*)(A + (size_t)(m0 + m) * K + k0 + kq * 8);
                    float4 f1 = *(const float4*)(A + (size_t)(m0 + m) * K + k0 + kq * 8 + 4);
                    v[0] = sf(f0.x); v[1] = sf(f0.y); v[2] = sf(f0.z); v[3] = sf(f0.w);
                    v[4] = sf(f1.x); v[5] = sf(f1.y); v[6] = sf(f1.z); v[7] = sf(f1.w);
                } else v = zero8();
            }
            *(bf8*)&As[m][kq * 8] = v;
            *(bf8*)&Ws[m][kq * 8] = *(const bf8*)(Wt + (size_t)(j0 + m) * K + k0 + kq * 8);
        }
        __syncthreads();
        bf8 af[4], bf[4];
#pragma unroll
        for (int fi = 0; fi < 4; ++fi)
            af[fi] = *(const bf8*)&As[wr * 64 + fi * 16 + lr][lg * 8];
#pragma unroll
        for (int fj = 0; fj < 4; ++fj)
            bf[fj] = *(const bf8*)&Ws[wc * 64 + fj * 16 + lr][lg * 8];
#pragma unroll
        for (int fi = 0; fi < 4; ++fi)
#pragma unroll
            for (int fj = 0; fj < 4; ++fj)
                acc[fi][fj] = MFMA(af[fi], bf[fj], acc[fi][fj]);
    }

    if (EPI == 0) {
        short* out = (short*)outv + (size_t)b * oStride;
#pragma unroll
        for (int fi = 0; fi < 4; ++fi)
#pragma unroll
            for (int reg = 0; reg < 4; ++reg) {
                int m = m0 + wr * 64 + fi * 16 + lg * 4 + reg;
                if (m < M) {
#pragma unroll
                    for (int fj = 0; fj < 4; ++fj)
                        out[(size_t)m * J + j0 + wc * 64 + fj * 16 + lr] = sf(acc[fi][fj][reg]);
                }
            }
    } else {
        float* out = (float*)outv + (size_t)b * oStride;
        const float* rp = res + (size_t)b * oStride;
        float bv[4];
#pragma unroll
        for (int fj = 0; fj < 4; ++fj) bv[fj] = bias[j0 + wc * 64 + fj * 16 + lr];
#pragma unroll
        for (int fi = 0; fi < 4; ++fi)
#pragma unroll
            for (int reg = 0; reg < 4; ++reg) {
                int m = m0 + wr * 64 + fi * 16 + lg * 4 + reg;
                size_t ro = (size_t)m * J + j0 + wc * 64;
#pragma unroll
                for (int fj = 0; fj < 4; ++fj) {
                    size_t idx = ro + fj * 16 + lr;
                    out[idx] = acc[fi][fj][reg] + bv[fj] + rp[idx];
                }
            }
    }
}

// ---------------------------------------------------------------------------
// per-head V transpose: src bf16 [b][n][Jfull] (col offset cb + h*64)
//                    -> dst bf16 [b][h][64][Np]  (zero-filled n >= Nsrc)
// ---------------------------------------------------------------------------
__global__ __launch_bounds__(256)
void vhead_t(const short* __restrict__ src, short* __restrict__ dst,
             int Nsrc, int Jfull, int cb, int Np)
{
    int n0 = blockIdx.x * 64, h = blockIdx.y, b = blockIdx.z;
    __shared__ short t[64][72];
    int tid = threadIdx.x;
    for (int l = tid; l < 512; l += 256) {
        int n = l >> 3, dq = l & 7;
        bf8 v = zero8();
        if (n0 + n < Nsrc)
            v = *(const bf8*)(src + ((size_t)b * Nsrc + n0 + n) * Jfull + cb + h * 64 + dq * 8);
        *(bf8*)&t[n][dq * 8] = v;
    }
    __syncthreads();
    for (int l = tid; l < 512; l += 256) {
        int d = l >> 3, nq = l & 7;
        if (n0 + nq * 8 < Np) {
            bf8 v;
#pragma unroll
            for (int i = 0; i < 8; ++i) {
                int j = (i + nq) & 7;               // bank stagger
                v[j] = t[nq * 8 + j][d];
            }
            *(bf8*)(dst + (((size_t)(b * 8 + h)) * 64 + d) * Np + n0 + nq * 8) = v;
        }
    }
}

// ---------------------------------------------------------------------------
// Fresnel attention, bf16 MFMA flash-style.
// Block: 4 waves x 16 q-rows (QT=64). K-tiles of 64 over N=1024.
// ---------------------------------------------------------------------------
__global__ __launch_bounds__(256)
void fresnel_attn_mfma(const short* __restrict__ qkv, const short* __restrict__ Vg,
                       const short* __restrict__ tab, short* __restrict__ ao)
{
    int qb = blockIdx.x, h = blockIdx.y, b = blockIdx.z;
    int n0 = qb * 64;
    __shared__ short Qs[64][72], Ks[64][72], Vt[64][72];
    __shared__ short Ps[4][16][72];
    __shared__ short tabs[3972];
    int tid = threadIdx.x, w = tid >> 6, lane = tid & 63;
    int lr = lane & 15, lg = lane >> 4;
    const short* qp = qkv + (size_t)b * N_ * 1536;
    const short* vp = Vg + ((size_t)(b * 8 + h)) * 64 * N_;

    for (int l = tid; l < 3969; l += 256) tabs[l] = tab[l];
    for (int l = tid; l < 512; l += 256) {
        int n = l >> 3, dq = l & 7;
        *(bf8*)&Qs[n][dq * 8] = *(const bf8*)(qp + (size_t)(n0 + n) * 1536 + h * 64 + dq * 8);
    }

    f4 o[4];
    float mrun[4], lrun[4];
#pragma unroll
    for (int i = 0; i < 4; ++i) { o[i] = zerof4(); mrun[i] = -1e30f; lrun[i] = 0.f; }

    for (int m0 = 0; m0 < N_; m0 += 64) {
        __syncthreads();
        for (int l = tid; l < 512; l += 256) {
            int r = l >> 3, q8 = l & 7;
            *(bf8*)&Ks[r][q8 * 8] = *(const bf8*)(qp + (size_t)(m0 + r) * 1536 + 512 + h * 64 + q8 * 8);
            *(bf8*)&Vt[r][q8 * 8] = *(const bf8*)(vp + (size_t)r * N_ + m0 + q8 * 8);
        }
        __syncthreads();

        f4 sacc[4];
#pragma unroll
        for (int fj = 0; fj < 4; ++fj) sacc[fj] = zerof4();
#pragma unroll
        for (int kc = 0; kc < 2; ++kc) {
            bf8 aq = *(const bf8*)&Qs[w * 16 + lr][kc * 32 + lg * 8];
#pragma unroll
            for (int fj = 0; fj < 4; ++fj)
                sacc[fj] = MFMA(aq, *(const bf8*)&Ks[fj * 16 + lr][kc * 32 + lg * 8], sacc[fj]);
        }

        int qgb = n0 + w * 16 + lg * 4;
#pragma unroll
        for (int reg = 0; reg < 4; ++reg) {
            int q = qgb + reg, qy = q >> 5, qx = q & 31;
            float sv[4];
#pragma unroll
            for (int fj = 0; fj < 4; ++fj) {
                int m = m0 + fj * 16 + lr;
                int idx = (qy - (m >> 5) + 31) * 63 + (qx - (m & 31) + 31);
                sv[fj] = sacc[fj][reg] * 0.125f + fs(tabs[idx]);
            }
            float mx = fmaxf(fmaxf(sv[0], sv[1]), fmaxf(sv[2], sv[3]));
#pragma unroll
            for (int off = 1; off < 16; off <<= 1) mx = fmaxf(mx, __shfl_xor(mx, off));
            float mnew = fmaxf(mrun[reg], mx);
            float r = __expf(mrun[reg] - mnew);
            float psum = 0.f;
#pragma unroll
            for (int fj = 0; fj < 4; ++fj) {
                float p = __expf(sv[fj] - mnew);
                psum += p;
                Ps[w][lg * 4 + reg][fj * 16 + lr] = sf(p);
            }
#pragma unroll
            for (int off = 1; off < 16; off <<= 1) psum += __shfl_xor(psum, off);
            lrun[reg] = lrun[reg] * r + psum;
            mrun[reg] = mnew;
#pragma unroll
            for (int fd = 0; fd < 4; ++fd) o[fd][reg] *= r;
        }

#pragma unroll
        for (int kc = 0; kc < 2; ++kc) {
            bf8 ap = *(const bf8*)&Ps[w][lr][kc * 32 + lg * 8];
#pragma unroll
            for (int fd = 0; fd < 4; ++fd)
                o[fd] = MFMA(ap, *(const bf8*)&Vt[fd * 16 + lr][kc * 32 + lg * 8], o[fd]);
        }
    }

#pragma unroll
    for (int reg = 0; reg < 4; ++reg) {
        float inv = 1.f / lrun[reg];
        size_t rb = ((size_t)b * N_ + n0 + w * 16 + lg * 4 + reg) * 512 + h * 64;
#pragma unroll
        for (int fd = 0; fd < 4; ++fd)
            ao[rb + fd * 16 + lr] = sf(o[fd][reg] * inv);
    }
}

// ---------------------------------------------------------------------------
// Cross attention, bf16 MFMA, single K-tile (L=77 padded to 96).
// ---------------------------------------------------------------------------
__global__ __launch_bounds__(256)
void cross_attn_mfma(const short* __restrict__ q2, const short* __restrict__ k2,
                     const short* __restrict__ v2t, short* __restrict__ ao2)
{
    int qb = blockIdx.x, h = blockIdx.y, b = blockIdx.z;
    int n0 = qb * 64;
    __shared__ short Qs[64][72], Ks[96][72], Vt[64][104];
    __shared__ short Ps[4][16][104];
    int tid = threadIdx.x, w = tid >> 6, lane = tid & 63;
    int lr = lane & 15, lg = lane >> 4;

    for (int l = tid; l < 512; l += 256) {
        int n = l >> 3, dq = l & 7;
        *(bf8*)&Qs[n][dq * 8] = *(const bf8*)(q2 + ((size_t)b * N_ + n0 + n) * 512 + h * 64 + dq * 8);
    }
    for (int l = tid; l < 768; l += 256) {
        int m = l >> 3, dq = l & 7;
        bf8 v = zero8();
        if (m < L_) v = *(const bf8*)(k2 + ((size_t)b * L_ + m) * 512 + h * 64 + dq * 8);
        *(bf8*)&Ks[m][dq * 8] = v;
    }
    for (int l = tid; l < 768; l += 256) {
        int d = l / 12, cq = l % 12;
        bf8 v = zero8();
        if (cq < 10) v = *(const bf8*)(v2t + (((size_t)(b * 8 + h)) * 64 + d) * 80 + cq * 8);
        *(bf8*)&Vt[d][cq * 8] = v;
    }
    __syncthreads();

    f4 sacc[6];
#pragma unroll
    for (int fj = 0; fj < 6; ++fj) sacc[fj] = zerof4();
#pragma unroll
    for (int kc = 0; kc < 2; ++kc) {
        bf8 aq = *(const bf8*)&Qs[w * 16 + lr][kc * 32 + lg * 8];
#pragma unroll
        for (int fj = 0; fj < 6; ++fj)
            sacc[fj] = MFMA(aq, *(const bf8*)&Ks[fj * 16 + lr][kc * 32 + lg * 8], sacc[fj]);
    }

    float rinv[4];
#pragma unroll
    for (int reg = 0; reg < 4; ++reg) {
        float sv[6];
#pragma unroll
        for (int fj = 0; fj < 6; ++fj) {
            int m = fj * 16 + lr;
            sv[fj] = (m < L_) ? sacc[fj][reg] * 0.125f : -30000.f;
        }
        float mx = sv[0];
#pragma unroll
        for (int fj = 1; fj < 6; ++fj) mx = fmaxf(mx, sv[fj]);
#pragma unroll
        for (int off = 1; off < 16; off <<= 1) mx = fmaxf(mx, __shfl_xor(mx, off));
        float psum = 0.f;
#pragma unroll
        for (int fj = 0; fj < 6; ++fj) {
            float p = __expf(sv[fj] - mx);
            psum += p;
            Ps[w][lg * 4 + reg][fj * 16 + lr] = sf(p);
        }
#pragma unroll
        for (int off = 1; off < 16; off <<= 1) psum += __shfl_xor(psum, off);
        rinv[reg] = 1.f / psum;
    }

    f4 o[4];
#pragma unroll
    for (int fd = 0; fd < 4; ++fd) o[fd] = zerof4();
#pragma unroll
    for (int kc = 0; kc < 3; ++kc) {
        bf8 ap = *(const bf8*)&Ps[w][lr][kc * 32 + lg * 8];
#pragma unroll
        for (int fd = 0; fd < 4; ++fd)
            o[fd] = MFMA(ap, *(const bf8*)&Vt[fd * 16 + lr][kc * 32 + lg * 8], o[fd]);
    }

#pragma unroll
    for (int reg = 0; reg < 4; ++reg) {
        size_t rb = ((size_t)b * N_ + n0 + w * 16 + lg * 4 + reg) * 512 + h * 64;
#pragma unroll
        for (int fd = 0; fd < 4; ++fd)
            ao2[rb + fd * 16 + lr] = sf(o[fd][reg] * rinv[reg]);
    }
}

// ---------------------------------------------------------------------------
extern "C" void kernel_launch(void* const* d_in, const int* in_sizes, int n_in,
                              void* d_out, int out_size, void* d_ws, size_t ws_size,
                              hipStream_t stream)
{
    const float* x    = (const float*)d_in[0];
    const float* ctx  = (const float*)d_in[1];
    const float* gn1w = (const float*)d_in[2];
    const float* gn1b = (const float*)d_in[3];
    const float* gn2w = (const float*)d_in[4];
    const float* gn2b = (const float*)d_in[5];
    const float* qkvw = (const float*)d_in[6];
    const float* faow = (const float*)d_in[7];
    const float* faob = (const float*)d_in[8];
    const float* wl   = (const float*)d_in[9];
    const float* caqw = (const float*)d_in[10];
    const float* cakw = (const float*)d_in[11];
    const float* cavw = (const float*)d_in[12];
    const float* caow = (const float*)d_in[13];
    const float* caob = (const float*)d_in[14];
    float* out = (float*)d_out;
    char* ws = (char*)d_ws;

    float* xT     = (float*)(ws + 0);                 // 8 MB fp32 [b][n][c]
    float* x1T    = (float*)(ws + 8388608);           // 8 MB
    short* qkvb   = (short*)(ws + 16777216);          // 12 MB bf16 [b][n][1536]
    float* finalT = (float*)(ws + 16777216);          // reuse (qkv dead by then)
    short* Vg     = (short*)(ws + 29360128);          // 4 MB [b][h][64][1024]
    short* h1b    = (short*)(ws + 33554432);          // 4 MB (also h2b)
    short* ao     = (short*)(ws + 37748736);          // 4 MB (also ao2)
    short* q2b    = (short*)(ws + 41943040);          // 4 MB
    short* qkvwT  = (short*)(ws + 46137344);
    short* faowT  = (short*)(ws + 47710208);
    short* caqwT  = (short*)(ws + 48234496);
    short* cakwT  = (short*)(ws + 48758784);
    short* cavwT  = (short*)(ws + 49545216);
    short* caowT  = (short*)(ws + 50331648);
    short* k2b    = (short*)(ws + 50855936);
    short* v2b    = (short*)(ws + 51171328);
    short* v2t    = (short*)(ws + 51486720);
    short* tab    = (short*)(ws + 52142080);

    tab_kernel<<<16, 256, 0, stream>>>(wl, tab);
    // xT = transpose(x): [c=512][n=1024] -> [n][c]
    transpose_f32<<<dim3(32, 16, 4), 256, 0, stream>>>(x, xT, 512, 1024);
    // weights -> bf16 [J][K]
    wtrans_kernel<<<dim3(48, 16), 256, 0, stream>>>(qkvw, qkvwT, 512, 1536);
    wtrans_kernel<<<dim3(16, 16), 256, 0, stream>>>(faow, faowT, 512, 512);
    wtrans_kernel<<<dim3(16, 16), 256, 0, stream>>>(caqw, caqwT, 512, 512);
    wtrans_kernel<<<dim3(16, 24), 256, 0, stream>>>(cakw, cakwT, 768, 512);
    wtrans_kernel<<<dim3(16, 24), 256, 0, stream>>>(cavw, cavwT, 768, 512);
    wtrans_kernel<<<dim3(16, 16), 256, 0, stream>>>(caow, caowT, 512, 512);

    groupnorm_nc<<<dim3(32, 4), 256, 0, stream>>>(xT, gn1w, gn1b, h1b);
    // qkv = h1 @ qkv_w : M=1024 K=512 J=1536
    gemm_mfma<false, 0><<<dim3(12, 8, 4), 256, 0, stream>>>(
        h1b, qkvwT, nullptr, nullptr, qkvb, 1024, 512, 1536, 524288L, 1572864L);
    vhead_t<<<dim3(16, 8, 4), 256, 0, stream>>>(qkvb, Vg, 1024, 1536, 1024, 1024);
    fresnel_attn_mfma<<<dim3(16, 8, 4), 256, 0, stream>>>(qkvb, Vg, tab, ao);
    // x1T = xT + ao @ fa_out_w + fa_out_b
    gemm_mfma<false, 1><<<dim3(4, 8, 4), 256, 0, stream>>>(
        ao, faowT, faob, xT, x1T, 1024, 512, 512, 524288L, 524288L);
    groupnorm_nc<<<dim3(32, 4), 256, 0, stream>>>(x1T, gn2w, gn2b, h1b);
    // q2 = h2 @ ca_q_w
    gemm_mfma<false, 0><<<dim3(4, 8, 4), 256, 0, stream>>>(
        h1b, caqwT, nullptr, nullptr, q2b, 1024, 512, 512, 524288L, 524288L);
    // k2/v2 = ctx @ ca_k/v_w : M=77 K=768 J=512  (fp32 A)
    gemm_mfma<true, 0><<<dim3(4, 1, 4), 256, 0, stream>>>(
        ctx, cakwT, nullptr, nullptr, k2b, 77, 768, 512, 59136L, 39424L);
    gemm_mfma<true, 0><<<dim3(4, 1, 4), 256, 0, stream>>>(
        ctx, cavwT, nullptr, nullptr, v2b, 77, 768, 512, 59136L, 39424L);
    vhead_t<<<dim3(2, 8, 4), 256, 0, stream>>>(v2b, v2t, 77, 512, 0, 80);
    cross_attn_mfma<<<dim3(16, 8, 4), 256, 0, stream>>>(q2b, k2b, v2t, ao);
    // finalT = x1T + ao2 @ ca_out_w + ca_out_b
    gemm_mfma<false, 1><<<dim3(4, 8, 4), 256, 0, stream>>>(
        ao, caowT, caob, x1T, finalT, 1024, 512, 512, 524288L, 524288L);
    // out = transpose(finalT): [n=1024][c=512] -> [c][n]
    transpose_f32<<<dim3(16, 32, 4), 256, 0, stream>>>(finalT, out, 1024, 512);
}

// Round 3
// 242.500 us; speedup vs baseline: 4.0291x; 1.3868x over previous
//
#include <hip/hip_runtime.h>
#include <hip/hip_bf16.h>
#include <math.h>

#define B_    4
#define N_    1024
#define L_    77

typedef float f4 __attribute__((ext_vector_type(4)));
typedef short bf8 __attribute__((ext_vector_type(8)));
typedef short s4v __attribute__((ext_vector_type(4)));

#if __has_builtin(__builtin_amdgcn_exp2f)
#define EXP2(x) __builtin_amdgcn_exp2f(x)
#else
#define EXP2(x) exp2f(x)
#endif

__device__ __forceinline__ float fs(short s) {
    unsigned u = ((unsigned)(unsigned short)s) << 16;
    return __builtin_bit_cast(float, u);
}
__device__ __forceinline__ short sf(float f) {
    unsigned u = __builtin_bit_cast(unsigned, f);
    unsigned r = (u + 0x7FFF + ((u >> 16) & 1)) >> 16;
    return (short)r;
}
__device__ __forceinline__ bf8 zero8() { bf8 v; for (int i = 0; i < 8; ++i) v[i] = 0; return v; }
__device__ __forceinline__ f4 zerof4() { f4 v; for (int i = 0; i < 4; ++i) v[i] = 0.f; return v; }

#define MFMA(a, b, c) __builtin_amdgcn_mfma_f32_16x16x32_bf16((a), (b), (c), 0, 0, 0)

// ---------------------------------------------------------------------------
// prep mega-kernel: tab (pre-scaled by log2e) + 6 weight transposes + ctx->bf16
// ---------------------------------------------------------------------------
__device__ __forceinline__ void wtile(const float* __restrict__ in, short* __restrict__ out,
                                      int K, int J, int tile, int tid, float (*t)[33])
{
    int jt = J >> 5;
    int j0 = (tile % jt) * 32, k0 = (tile / jt) * 32;
    int tx = tid & 31, ty = tid >> 5;
#pragma unroll
    for (int i = 0; i < 4; ++i)
        t[ty + i * 8][tx] = in[(size_t)(k0 + ty + i * 8) * J + j0 + tx];
    __syncthreads();
#pragma unroll
    for (int i = 0; i < 4; ++i)
        out[(size_t)(j0 + ty + i * 8) * K + k0 + tx] = sf(t[tx][ty + i * 8]);
}

__global__ __launch_bounds__(256)
void prep_mega(const float* __restrict__ wl, short* __restrict__ tab,
               const float* __restrict__ qkvw, short* __restrict__ qkvwT,
               const float* __restrict__ faow, short* __restrict__ faowT,
               const float* __restrict__ caqw, short* __restrict__ caqwT,
               const float* __restrict__ cakw, short* __restrict__ cakwT,
               const float* __restrict__ cavw, short* __restrict__ cavwT,
               const float* __restrict__ caow, short* __restrict__ caowT,
               const float* __restrict__ ctx, short* __restrict__ ctxb)
{
    __shared__ float tls[32][33];
    int bid = blockIdx.x, tid = threadIdx.x;
    if (bid < 16) {
        int idx = bid * 256 + tid;
        if (idx < 3969) {
            int i = idx / 63, j = idx - i * 63;
            float dy = (float)(i - 31), dx = (float)(j - 31);
            float dist = sqrtf(dy * dy + dx * dx + 1e-8f);
            float den = fabsf(wl[0]) * 32.0f + 1e-6f;
            tab[idx] = sf(0.1f * cosf(6.283185307179586f * dist / den) * 1.4426950408889634f);
        }
        return;
    }
    bid -= 16;
    if (bid < 768) { wtile(qkvw, qkvwT, 512, 1536, bid, tid, tls); return; }
    bid -= 768;
    if (bid < 256) { wtile(faow, faowT, 512, 512, bid, tid, tls); return; }
    bid -= 256;
    if (bid < 256) { wtile(caqw, caqwT, 512, 512, bid, tid, tls); return; }
    bid -= 256;
    if (bid < 384) { wtile(cakw, cakwT, 768, 512, bid, tid, tls); return; }
    bid -= 384;
    if (bid < 384) { wtile(cavw, cavwT, 768, 512, bid, tid, tls); return; }
    bid -= 384;
    if (bid < 256) { wtile(caow, caowT, 512, 512, bid, tid, tls); return; }
    bid -= 256;
    // ctx convert: 231 blocks x 1024 elems
    int base = bid * 1024 + tid * 4;
    float4 v = *(const float4*)(ctx + base);
    s4v o; o[0] = sf(v.x); o[1] = sf(v.y); o[2] = sf(v.z); o[3] = sf(v.w);
    *(s4v*)(ctxb + base) = o;
}

// ---------------------------------------------------------------------------
// fused GroupNorm1 + transpose: reads x [b][c][n], writes xT fp32 [n][c] and
// h1b bf16 [n][c]. One block per (group, batch).
// ---------------------------------------------------------------------------
__global__ __launch_bounds__(256)
void gn1_fused(const float* __restrict__ x, const float* __restrict__ w,
               const float* __restrict__ bs, float* __restrict__ xT,
               short* __restrict__ h1b)
{
    int g = blockIdx.x, b = blockIdx.y;
    const float* xb = x + ((size_t)b * 512 + g * 16) * 1024;
    float s = 0.f, ss = 0.f;
    for (int l = threadIdx.x; l < 4096; l += 256) {
        float4 v = *(const float4*)(xb + l * 4);
        s += v.x + v.y + v.z + v.w;
        ss += v.x * v.x + v.y * v.y + v.z * v.z + v.w * v.w;
    }
    for (int off = 32; off; off >>= 1) {
        s  += __shfl_down(s,  off);
        ss += __shfl_down(ss, off);
    }
    __shared__ float sred[8], ssred[8];
    int wid = threadIdx.x >> 6;
    if ((threadIdx.x & 63) == 0) { sred[wid] = s; ssred[wid] = ss; }
    __syncthreads();
    if (threadIdx.x == 0) {
        float S = 0.f, SS = 0.f;
        for (int i = 0; i < 4; ++i) { S += sred[i]; SS += ssred[i]; }
        float mu = S * (1.f / 16384.f);
        float var = SS * (1.f / 16384.f) - mu * mu;
        sred[4] = mu; ssred[4] = rsqrtf(var + 1e-5f);
    }
    __syncthreads();
    float mu = sred[4], rs = ssred[4];

    int c4 = threadIdx.x & 3, nb = threadIdx.x >> 2;
    int c = g * 16 + c4 * 4;
    float4 wv = *(const float4*)(w + c);
    float4 bv = *(const float4*)(bs + c);
    for (int rep = 0; rep < 16; ++rep) {
        int n = rep * 64 + nb;
        float v0 = xb[(size_t)(c4 * 4 + 0) * 1024 + n];
        float v1 = xb[(size_t)(c4 * 4 + 1) * 1024 + n];
        float v2 = xb[(size_t)(c4 * 4 + 2) * 1024 + n];
        float v3 = xb[(size_t)(c4 * 4 + 3) * 1024 + n];
        float4 y;
        y.x = (v0 - mu) * rs * wv.x + bv.x;
        y.y = (v1 - mu) * rs * wv.y + bv.y;
        y.z = (v2 - mu) * rs * wv.z + bv.z;
        y.w = (v3 - mu) * rs * wv.w + bv.w;
        size_t ro = ((size_t)b * 1024 + n) * 512 + c;
        *(float4*)(xT + ro) = y;
        s4v hb; hb[0] = sf(y.x); hb[1] = sf(y.y); hb[2] = sf(y.z); hb[3] = sf(y.w);
        *(s4v*)(h1b + ro) = hb;
    }
}

// ---------------------------------------------------------------------------
// GroupNorm over [n][c] fp32 -> bf16 [n][c]  (for gn2)
// ---------------------------------------------------------------------------
__global__ __launch_bounds__(256)
void groupnorm_nc(const float* __restrict__ x, const float* __restrict__ w,
                  const float* __restrict__ bs, short* __restrict__ out)
{
    int g = blockIdx.x, b = blockIdx.y;
    const float* xb = x + (size_t)b * 524288 + g * 16;
    short* ob = out + (size_t)b * 524288 + g * 16;
    float s = 0.f, ss = 0.f;
    for (int l = threadIdx.x; l < 4096; l += 256) {
        int n = l >> 2, c4 = l & 3;
        float4 v = *(const float4*)(xb + (size_t)n * 512 + c4 * 4);
        s += v.x + v.y + v.z + v.w;
        ss += v.x * v.x + v.y * v.y + v.z * v.z + v.w * v.w;
    }
    for (int off = 32; off; off >>= 1) {
        s  += __shfl_down(s,  off);
        ss += __shfl_down(ss, off);
    }
    __shared__ float sred[8], ssred[8];
    int wid = threadIdx.x >> 6;
    if ((threadIdx.x & 63) == 0) { sred[wid] = s; ssred[wid] = ss; }
    __syncthreads();
    if (threadIdx.x == 0) {
        float S = 0.f, SS = 0.f;
        for (int i = 0; i < 4; ++i) { S += sred[i]; SS += ssred[i]; }
        float mu = S * (1.f / 16384.f);
        float var = SS * (1.f / 16384.f) - mu * mu;
        sred[4] = mu; ssred[4] = rsqrtf(var + 1e-5f);
    }
    __syncthreads();
    float mu = sred[4], rs = ssred[4];
    for (int l = threadIdx.x; l < 4096; l += 256) {
        int n = l >> 2, c4 = l & 3, c = g * 16 + c4 * 4;
        float4 v = *(const float4*)(xb + (size_t)n * 512 + c4 * 4);
        s4v o;
        o[0] = sf((v.x - mu) * rs * w[c + 0] + bs[c + 0]);
        o[1] = sf((v.y - mu) * rs * w[c + 1] + bs[c + 1]);
        o[2] = sf((v.z - mu) * rs * w[c + 2] + bs[c + 2]);
        o[3] = sf((v.w - mu) * rs * w[c + 3] + bs[c + 3]);
        *(s4v*)(ob + (size_t)n * 512 + c4 * 4) = o;
    }
}

// ---------------------------------------------------------------------------
// fp32 transpose per batch: in [R][C] -> out [C][R]  (final output only)
// ---------------------------------------------------------------------------
__global__ __launch_bounds__(256)
void transpose_f32(const float* __restrict__ in, float* __restrict__ out, int R, int C)
{
    __shared__ float t[32][33];
    int tx = threadIdx.x & 31, ty = threadIdx.x >> 5;
    int r0 = blockIdx.y * 32, c0 = blockIdx.x * 32;
    size_t bo = (size_t)blockIdx.z * R * C;
#pragma unroll
    for (int i = 0; i < 4; ++i)
        t[ty + i * 8][tx] = in[bo + (size_t)(r0 + ty + i * 8) * C + c0 + tx];
    __syncthreads();
#pragma unroll
    for (int i = 0; i < 4; ++i)
        out[bo + (size_t)(c0 + ty + i * 8) * R + r0 + tx] = t[tx][ty + i * 8];
}

// ---------------------------------------------------------------------------
// MFMA GEMM, double-buffered LDS, one barrier per K-step.
// out[b][m][j] = sum_k A[b][m][k] * Wt[j][k]
// EPI 0: bf16 store.  EPI 1: fp32 store + bias[j] + res[b][m][j].
// ---------------------------------------------------------------------------
template<int EPI>
__global__ __launch_bounds__(256)
void gemm_mfma(const short* __restrict__ A, const short* __restrict__ Wt,
               const float* __restrict__ bias, const float* __restrict__ res,
               void* __restrict__ outv, int M, int K, int J,
               long aStride, long oStride)
{
    int j0 = blockIdx.x * 128, m0 = blockIdx.y * 128, b = blockIdx.z;
    __shared__ short As[2][128][40];
    __shared__ short Ws[2][128][40];
    int tid = threadIdx.x, w = tid >> 6, lane = tid & 63;
    int lr = lane & 15, lg = lane >> 4;
    int wr = w >> 1, wc = w & 1;
    const short* Ab = A + (size_t)b * aStride;
    int r0 = tid >> 2, c0 = (tid & 3) * 8;
    int r1 = 64 + r0;
    bool gA0 = (m0 + r0) < M, gA1 = (m0 + r1) < M;
    const short* ap0 = Ab + (size_t)(m0 + r0) * K + c0;
    const short* ap1 = Ab + (size_t)(m0 + r1) * K + c0;
    const short* wp0 = Wt + (size_t)(j0 + r0) * K + c0;
    const short* wp1 = Wt + (size_t)(j0 + r1) * K + c0;

    f4 acc[4][4];
#pragma unroll
    for (int i = 0; i < 4; ++i)
#pragma unroll
        for (int j = 0; j < 4; ++j) acc[i][j] = zerof4();

    *(bf8*)&As[0][r0][c0] = gA0 ? *(const bf8*)ap0 : zero8();
    *(bf8*)&As[0][r1][c0] = gA1 ? *(const bf8*)ap1 : zero8();
    *(bf8*)&Ws[0][r0][c0] = *(const bf8*)wp0;
    *(bf8*)&Ws[0][r1][c0] = *(const bf8*)wp1;
    __syncthreads();

    int nk = K >> 5;
    for (int t = 0; t < nk; ++t) {
        int cur = t & 1;
        bool more = (t + 1) < nk;
        bf8 na0, na1, nw0, nw1;
        if (more) {
            int ko = (t + 1) << 5;
            na0 = gA0 ? *(const bf8*)(ap0 + ko) : zero8();
            na1 = gA1 ? *(const bf8*)(ap1 + ko) : zero8();
            nw0 = *(const bf8*)(wp0 + ko);
            nw1 = *(const bf8*)(wp1 + ko);
        }
        bf8 af[4], bfr[4];
#pragma unroll
        for (int fi = 0; fi < 4; ++fi)
            af[fi] = *(const bf8*)&As[cur][wr * 64 + fi * 16 + lr][lg * 8];
#pragma unroll
        for (int fj = 0; fj < 4; ++fj)
            bfr[fj] = *(const bf8*)&Ws[cur][wc * 64 + fj * 16 + lr][lg * 8];
#pragma unroll
        for (int fi = 0; fi < 4; ++fi)
#pragma unroll
            for (int fj = 0; fj < 4; ++fj)
                acc[fi][fj] = MFMA(af[fi], bfr[fj], acc[fi][fj]);
        if (more) {
            int nb = cur ^ 1;
            *(bf8*)&As[nb][r0][c0] = na0;
            *(bf8*)&As[nb][r1][c0] = na1;
            *(bf8*)&Ws[nb][r0][c0] = nw0;
            *(bf8*)&Ws[nb][r1][c0] = nw1;
        }
        __syncthreads();
    }

    if (EPI == 0) {
        short* out = (short*)outv + (size_t)b * oStride;
#pragma unroll
        for (int fi = 0; fi < 4; ++fi)
#pragma unroll
            for (int reg = 0; reg < 4; ++reg) {
                int m = m0 + wr * 64 + fi * 16 + lg * 4 + reg;
                if (m < M) {
#pragma unroll
                    for (int fj = 0; fj < 4; ++fj)
                        out[(size_t)m * J + j0 + wc * 64 + fj * 16 + lr] = sf(acc[fi][fj][reg]);
                }
            }
    } else {
        float* out = (float*)outv + (size_t)b * oStride;
        const float* rp = res + (size_t)b * oStride;
        float bv[4];
#pragma unroll
        for (int fj = 0; fj < 4; ++fj) bv[fj] = bias[j0 + wc * 64 + fj * 16 + lr];
#pragma unroll
        for (int fi = 0; fi < 4; ++fi)
#pragma unroll
            for (int reg = 0; reg < 4; ++reg) {
                int m = m0 + wr * 64 + fi * 16 + lg * 4 + reg;
                size_t ro = (size_t)m * J + j0 + wc * 64;
#pragma unroll
                for (int fj = 0; fj < 4; ++fj) {
                    size_t idx = ro + fj * 16 + lr;
                    out[idx] = acc[fi][fj][reg] + bv[fj] + rp[idx];
                }
            }
    }
}

// ---------------------------------------------------------------------------
// per-head V transpose: src bf16 [b][n][Jfull] (col offset cb + h*64)
//                    -> dst bf16 [b][h][64][Np]  (zero-filled n >= Nsrc)
// ---------------------------------------------------------------------------
__global__ __launch_bounds__(256)
void vhead_t(const short* __restrict__ src, short* __restrict__ dst,
             int Nsrc, int Jfull, int cb, int Np)
{
    int n0 = blockIdx.x * 64, h = blockIdx.y, b = blockIdx.z;
    __shared__ short t[64][72];
    int tid = threadIdx.x;
    for (int l = tid; l < 512; l += 256) {
        int n = l >> 3, dq = l & 7;
        bf8 v = zero8();
        if (n0 + n < Nsrc)
            v = *(const bf8*)(src + ((size_t)b * Nsrc + n0 + n) * Jfull + cb + h * 64 + dq * 8);
        *(bf8*)&t[n][dq * 8] = v;
    }
    __syncthreads();
    for (int l = tid; l < 512; l += 256) {
        int d = l >> 3, nq = l & 7;
        if (n0 + nq * 8 < Np) {
            bf8 v;
#pragma unroll
            for (int i = 0; i < 8; ++i) {
                int j = (i + nq) & 7;               // bank stagger
                v[j] = t[nq * 8 + j][d];
            }
            *(bf8*)(dst + (((size_t)(b * 8 + h)) * 64 + d) * Np + n0 + nq * 8) = v;
        }
    }
}

// ---------------------------------------------------------------------------
// Fresnel attention v2: swapped QK^T (lane owns one query), in-lane softmax,
// double-buffered swizzled K/V LDS, one barrier per 64-key tile.
// ---------------------------------------------------------------------------
__global__ __launch_bounds__(256)
void fresnel_attn_v2(const short* __restrict__ qkv, const short* __restrict__ Vg,
                     const short* __restrict__ tab, short* __restrict__ ao)
{
    int qb = blockIdx.x, h = blockIdx.y, b = blockIdx.z;
    int n0 = qb * 64;
    __shared__ short Ks[2][64][64];
    __shared__ short Vt[2][64][64];
    __shared__ short Ps[4][16][72];
    __shared__ short tabs[3969];
    int tid = threadIdx.x, w = tid >> 6, lane = tid & 63;
    int lr = lane & 15, lg = lane >> 4;
    const short* qp = qkv + (size_t)b * N_ * 1536;
    const short* vp = Vg + ((size_t)(b * 8 + h)) * 65536;

    for (int l = tid; l < 3969; l += 256) tabs[l] = tab[l];

    int q = n0 + w * 16 + lr;                 // this lane's query row
    bf8 qf0 = *(const bf8*)(qp + (size_t)q * 1536 + h * 64 + lg * 8);
    bf8 qf1 = *(const bf8*)(qp + (size_t)q * 1536 + h * 64 + 32 + lg * 8);

    // staging: 512 chunks (64 rows x 8), 2 K + 2 V chunks per thread
    int sr0 = tid >> 3, sc0 = tid & 7;
    int sr1 = 32 + sr0;
    int sw0 = ((sc0 ^ (sr0 & 7))) * 8;
    int sw1 = ((sc0 ^ (sr1 & 7))) * 8;

    *(bf8*)&Ks[0][sr0][sw0] = *(const bf8*)(qp + (size_t)sr0 * 1536 + 512 + h * 64 + sc0 * 8);
    *(bf8*)&Ks[0][sr1][sw1] = *(const bf8*)(qp + (size_t)sr1 * 1536 + 512 + h * 64 + sc0 * 8);
    *(bf8*)&Vt[0][sr0][sw0] = *(const bf8*)(vp + (size_t)sr0 * 1024 + sc0 * 8);
    *(bf8*)&Vt[0][sr1][sw1] = *(const bf8*)(vp + (size_t)sr1 * 1024 + sc0 * 8);
    __syncthreads();

    float mrun = -1e30f, lrun = 0.f;          // log2 domain
    f4 o[4];
#pragma unroll
    for (int i = 0; i < 4; ++i) o[i] = zerof4();

    int ybase = (q >> 5) + 31;
    int xbase = (q & 31) + 31 - lg * 4;
    int rsw = lr & 7;
    int rc0 = (lg ^ rsw) * 8;                 // kc=0 swizzled chunk offset
    int rc1 = ((4 + lg) ^ rsw) * 8;           // kc=1

    for (int t = 0; t < 16; ++t) {
        int cur = t & 1;
        int m0 = t << 6;
        bool more = t < 15;
        bf8 nk0, nk1, nv0, nv1;
        if (more) {
            int m1 = m0 + 64;
            nk0 = *(const bf8*)(qp + (size_t)(m1 + sr0) * 1536 + 512 + h * 64 + sc0 * 8);
            nk1 = *(const bf8*)(qp + (size_t)(m1 + sr1) * 1536 + 512 + h * 64 + sc0 * 8);
            nv0 = *(const bf8*)(vp + (size_t)sr0 * 1024 + m1 + sc0 * 8);
            nv1 = *(const bf8*)(vp + (size_t)sr1 * 1024 + m1 + sc0 * 8);
        }

        // QK^T swapped: D[key][query], lane holds query lr, keys fj*16+lg*4+reg
        f4 sa[4];
#pragma unroll
        for (int fj = 0; fj < 4; ++fj) sa[fj] = zerof4();
#pragma unroll
        for (int fj = 0; fj < 4; ++fj)
            sa[fj] = MFMA(*(const bf8*)&Ks[cur][fj * 16 + lr][rc0], qf0, sa[fj]);
#pragma unroll
        for (int fj = 0; fj < 4; ++fj)
            sa[fj] = MFMA(*(const bf8*)&Ks[cur][fj * 16 + lr][rc1], qf1, sa[fj]);

        // scores in log2 domain + interference
        int yb = ybase - (m0 >> 5);
        float pv[4][4];
        float tmax = -1e30f;
#pragma unroll
        for (int fj = 0; fj < 4; ++fj) {
            int rowoff = (yb - (fj >> 1)) * 63 + xbase - (fj & 1) * 16;
#pragma unroll
            for (int reg = 0; reg < 4; ++reg) {
                float t2 = fmaf(sa[fj][reg], 0.18033688011112042f, fs(tabs[rowoff - reg]));
                pv[fj][reg] = t2;
                tmax = fmaxf(tmax, t2);
            }
        }
        tmax = fmaxf(tmax, __shfl_xor(tmax, 16));
        tmax = fmaxf(tmax, __shfl_xor(tmax, 32));
        float mnew = fmaxf(mrun, tmax);
        float rsc = EXP2(mrun - mnew);
        mrun = mnew;
        float psum = 0.f;
#pragma unroll
        for (int fj = 0; fj < 4; ++fj) {
            s4v pw;
#pragma unroll
            for (int reg = 0; reg < 4; ++reg) {
                float p = EXP2(pv[fj][reg] - mnew);
                psum += p;
                pw[reg] = sf(p);
            }
            *(s4v*)&Ps[w][lr][fj * 16 + lg * 4] = pw;   // row = query lr
        }
        psum += __shfl_xor(psum, 16);
        psum += __shfl_xor(psum, 32);
        lrun = lrun * rsc + psum;
#pragma unroll
        for (int fd = 0; fd < 4; ++fd)
#pragma unroll
            for (int reg = 0; reg < 4; ++reg) o[fd][reg] *= rsc;

        // PV: O^T[d][q] = mfma(Vt rows=d, P cols=q)
        bf8 pa0 = *(const bf8*)&Ps[w][lr][lg * 8];
        bf8 pa1 = *(const bf8*)&Ps[w][lr][32 + lg * 8];
#pragma unroll
        for (int fd = 0; fd < 4; ++fd) {
            o[fd] = MFMA(*(const bf8*)&Vt[cur][fd * 16 + lr][rc0], pa0, o[fd]);
            o[fd] = MFMA(*(const bf8*)&Vt[cur][fd * 16 + lr][rc1], pa1, o[fd]);
        }

        if (more) {
            int nb = cur ^ 1;
            *(bf8*)&Ks[nb][sr0][sw0] = nk0;
            *(bf8*)&Ks[nb][sr1][sw1] = nk1;
            *(bf8*)&Vt[nb][sr0][sw0] = nv0;
            *(bf8*)&Vt[nb][sr1][sw1] = nv1;
        }
        __syncthreads();
    }

    float inv = 1.f / lrun;
    size_t rb = ((size_t)b * N_ + q) * 512 + h * 64;
#pragma unroll
    for (int fd = 0; fd < 4; ++fd) {
        s4v ov;
#pragma unroll
        for (int reg = 0; reg < 4; ++reg) ov[reg] = sf(o[fd][reg] * inv);
        *(s4v*)(ao + rb + fd * 16 + lg * 4) = ov;
    }
}

// ---------------------------------------------------------------------------
// Cross attention, bf16 MFMA, single K-tile (L=77 padded to 96).
// kv: [b][77][1024] combined (k at h*64, v at 512+h*64); v2t: [b][h][64][80]
// ---------------------------------------------------------------------------
__global__ __launch_bounds__(256)
void cross_attn_mfma(const short* __restrict__ q2, const short* __restrict__ kv,
                     const short* __restrict__ v2t, short* __restrict__ ao2)
{
    int qb = blockIdx.x, h = blockIdx.y, b = blockIdx.z;
    int n0 = qb * 64;
    __shared__ short Qs[64][72], Ks[96][72], Vt[64][104];
    __shared__ short Ps[4][16][104];
    int tid = threadIdx.x, w = tid >> 6, lane = tid & 63;
    int lr = lane & 15, lg = lane >> 4;

    for (int l = tid; l < 512; l += 256) {
        int n = l >> 3, dq = l & 7;
        *(bf8*)&Qs[n][dq * 8] = *(const bf8*)(q2 + ((size_t)b * N_ + n0 + n) * 512 + h * 64 + dq * 8);
    }
    for (int l = tid; l < 768; l += 256) {
        int m = l >> 3, dq = l & 7;
        bf8 v = zero8();
        if (m < L_) v = *(const bf8*)(kv + ((size_t)b * L_ + m) * 1024 + h * 64 + dq * 8);
        *(bf8*)&Ks[m][dq * 8] = v;
    }
    for (int l = tid; l < 768; l += 256) {
        int d = l / 12, cq = l % 12;
        bf8 v = zero8();
        if (cq < 10) v = *(const bf8*)(v2t + (((size_t)(b * 8 + h)) * 64 + d) * 80 + cq * 8);
        *(bf8*)&Vt[d][cq * 8] = v;
    }
    __syncthreads();

    f4 sacc[6];
#pragma unroll
    for (int fj = 0; fj < 6; ++fj) sacc[fj] = zerof4();
#pragma unroll
    for (int kc = 0; kc < 2; ++kc) {
        bf8 aq = *(const bf8*)&Qs[w * 16 + lr][kc * 32 + lg * 8];
#pragma unroll
        for (int fj = 0; fj < 6; ++fj)
            sacc[fj] = MFMA(aq, *(const bf8*)&Ks[fj * 16 + lr][kc * 32 + lg * 8], sacc[fj]);
    }

    float rinv[4];
#pragma unroll
    for (int reg = 0; reg < 4; ++reg) {
        float sv[6];
#pragma unroll
        for (int fj = 0; fj < 6; ++fj) {
            int m = fj * 16 + lr;
            sv[fj] = (m < L_) ? sacc[fj][reg] * 0.125f : -30000.f;
        }
        float mx = sv[0];
#pragma unroll
        for (int fj = 1; fj < 6; ++fj) mx = fmaxf(mx, sv[fj]);
#pragma unroll
        for (int off = 1; off < 16; off <<= 1) mx = fmaxf(mx, __shfl_xor(mx, off));
        float psum = 0.f;
#pragma unroll
        for (int fj = 0; fj < 6; ++fj) {
            float p = __expf(sv[fj] - mx);
            psum += p;
            Ps[w][lg * 4 + reg][fj * 16 + lr] = sf(p);
        }
#pragma unroll
        for (int off = 1; off < 16; off <<= 1) psum += __shfl_xor(psum, off);
        rinv[reg] = 1.f / psum;
    }
    __syncthreads();

    f4 o[4];
#pragma unroll
    for (int fd = 0; fd < 4; ++fd) o[fd] = zerof4();
#pragma unroll
    for (int kc = 0; kc < 3; ++kc) {
        bf8 ap = *(const bf8*)&Ps[w][lr][kc * 32 + lg * 8];
#pragma unroll
        for (int fd = 0; fd < 4; ++fd)
            o[fd] = MFMA(ap, *(const bf8*)&Vt[fd * 16 + lr][kc * 32 + lg * 8], o[fd]);
    }

#pragma unroll
    for (int reg = 0; reg < 4; ++reg) {
        size_t rb = ((size_t)b * N_ + n0 + w * 16 + lg * 4 + reg) * 512 + h * 64;
#pragma unroll
        for (int fd = 0; fd < 4; ++fd)
            ao2[rb + fd * 16 + lr] = sf(o[fd][reg] * rinv[reg]);
    }
}

// ---------------------------------------------------------------------------
extern "C" void kernel_launch(void* const* d_in, const int* in_sizes, int n_in,
                              void* d_out, int out_size, void* d_ws, size_t ws_size,
                              hipStream_t stream)
{
    const float* x    = (const float*)d_in[0];
    const float* ctx  = (const float*)d_in[1];
    const float* gn1w = (const float*)d_in[2];
    const float* gn1b = (const float*)d_in[3];
    const float* gn2w = (const float*)d_in[4];
    const float* gn2b = (const float*)d_in[5];
    const float* qkvw = (const float*)d_in[6];
    const float* faow = (const float*)d_in[7];
    const float* faob = (const float*)d_in[8];
    const float* wl   = (const float*)d_in[9];
    const float* caqw = (const float*)d_in[10];
    const float* cakw = (const float*)d_in[11];
    const float* cavw = (const float*)d_in[12];
    const float* caow = (const float*)d_in[13];
    const float* caob = (const float*)d_in[14];
    float* out = (float*)d_out;
    char* ws = (char*)d_ws;

    float* xT     = (float*)(ws + 0);                 // 8 MB fp32 [b][n][c]
    float* x1T    = (float*)(ws + 8388608);           // 8 MB
    short* qkvb   = (short*)(ws + 16777216);          // 12 MB bf16 [b][n][1536]
    float* finalT = (float*)(ws + 16777216);          // reuse (qkv dead by then)
    short* Vg     = (short*)(ws + 29360128);          // 4 MB [b][h][64][1024]
    short* h1b    = (short*)(ws + 33554432);          // 4 MB (also h2b)
    short* ao     = (short*)(ws + 37748736);          // 4 MB (also ao2)
    short* q2b    = (short*)(ws + 41943040);          // 4 MB
    short* qkvwT  = (short*)(ws + 46137344);          // 1.5 MB
    short* faowT  = (short*)(ws + 47710208);          // 0.5 MB
    short* caqwT  = (short*)(ws + 48234496);          // 0.5 MB
    short* cakwT  = (short*)(ws + 48758784);          // 0.75 MB
    short* cavwT  = (short*)(ws + 49545216);          // 0.75 MB (contiguous w/ cakwT)
    short* caowT  = (short*)(ws + 50331648);          // 0.5 MB
    short* kv2b   = (short*)(ws + 50855936);          // 616 KB [b][77][1024]
    short* v2t    = (short*)(ws + 51486720);          // 320 KB [b][h][64][80]
    short* ctxb   = (short*)(ws + 51814400);          // 462 KB
    short* tab    = (short*)(ws + 52287488);          // 8 KB

    prep_mega<<<2551, 256, 0, stream>>>(wl, tab, qkvw, qkvwT, faow, faowT,
                                        caqw, caqwT, cakw, cakwT, cavw, cavwT,
                                        caow, caowT, ctx, ctxb);
    gn1_fused<<<dim3(32, 4), 256, 0, stream>>>(x, gn1w, gn1b, xT, h1b);
    // qkv = h1 @ qkv_w : M=1024 K=512 J=1536
    gemm_mfma<0><<<dim3(12, 8, 4), 256, 0, stream>>>(
        h1b, qkvwT, nullptr, nullptr, qkvb, 1024, 512, 1536, 524288L, 1572864L);
    vhead_t<<<dim3(16, 8, 4), 256, 0, stream>>>(qkvb, Vg, 1024, 1536, 1024, 1024);
    fresnel_attn_v2<<<dim3(16, 8, 4), 256, 0, stream>>>(qkvb, Vg, tab, ao);
    // x1T = xT + ao @ fa_out_w + fa_out_b
    gemm_mfma<1><<<dim3(4, 8, 4), 256, 0, stream>>>(
        ao, faowT, faob, xT, x1T, 1024, 512, 512, 524288L, 524288L);
    groupnorm_nc<<<dim3(32, 4), 256, 0, stream>>>(x1T, gn2w, gn2b, h1b);
    // q2 = h2 @ ca_q_w
    gemm_mfma<0><<<dim3(4, 8, 4), 256, 0, stream>>>(
        h1b, caqwT, nullptr, nullptr, q2b, 1024, 512, 512, 524288L, 524288L);
    // k2|v2 = ctx @ [ca_k_w | ca_v_w] : M=77 K=768 J=1024 combined
    gemm_mfma<0><<<dim3(8, 1, 4), 256, 0, stream>>>(
        ctxb, cakwT, nullptr, nullptr, kv2b, 77, 768, 1024, 59136L, 78848L);
    vhead_t<<<dim3(2, 8, 4), 256, 0, stream>>>(kv2b, v2t, 77, 1024, 512, 80);
    cross_attn_mfma<<<dim3(16, 8, 4), 256, 0, stream>>>(q2b, kv2b, v2t, ao);
    // finalT = x1T + ao2 @ ca_out_w + ca_out_b
    gemm_mfma<1><<<dim3(4, 8, 4), 256, 0, stream>>>(
        ao, caowT, caob, x1T, finalT, 1024, 512, 512, 524288L, 524288L);
    // out = transpose(finalT): [n=1024][c=512] -> [c][n]
    transpose_f32<<<dim3(16, 32, 4), 256, 0, stream>>>(finalT, out, 1024, 512);
}

// Round 4
// 223.256 us; speedup vs baseline: 4.3764x; 1.0862x over previous
//
#include <hip/hip_runtime.h>
#include <hip/hip_bf16.h>
#include <math.h>

#define B_    4
#define N_    1024
#define L_    77

typedef float f4 __attribute__((ext_vector_type(4)));
typedef short bf8 __attribute__((ext_vector_type(8)));
typedef short s4v __attribute__((ext_vector_type(4)));

#if __has_builtin(__builtin_amdgcn_exp2f)
#define EXP2(x) __builtin_amdgcn_exp2f(x)
#else
#define EXP2(x) exp2f(x)
#endif

__device__ __forceinline__ float fs(short s) {
    unsigned u = ((unsigned)(unsigned short)s) << 16;
    return __builtin_bit_cast(float, u);
}
__device__ __forceinline__ short sf(float f) {
    unsigned u = __builtin_bit_cast(unsigned, f);
    unsigned r = (u + 0x7FFF + ((u >> 16) & 1)) >> 16;
    return (short)r;
}
__device__ __forceinline__ bf8 zero8() { bf8 v; for (int i = 0; i < 8; ++i) v[i] = 0; return v; }
__device__ __forceinline__ f4 zerof4() { f4 v; for (int i = 0; i < 4; ++i) v[i] = 0.f; return v; }

#define MFMA(a, b, c) __builtin_amdgcn_mfma_f32_16x16x32_bf16((a), (b), (c), 0, 0, 0)

// ---------------------------------------------------------------------------
// prep mega-kernel: tab (pre-scaled by log2e) + 6 weight transposes + ctx->bf16
// ---------------------------------------------------------------------------
__device__ __forceinline__ void wtile(const float* __restrict__ in, short* __restrict__ out,
                                      int K, int J, int tile, int tid, float (*t)[33])
{
    int jt = J >> 5;
    int j0 = (tile % jt) * 32, k0 = (tile / jt) * 32;
    int tx = tid & 31, ty = tid >> 5;
#pragma unroll
    for (int i = 0; i < 4; ++i)
        t[ty + i * 8][tx] = in[(size_t)(k0 + ty + i * 8) * J + j0 + tx];
    __syncthreads();
#pragma unroll
    for (int i = 0; i < 4; ++i)
        out[(size_t)(j0 + ty + i * 8) * K + k0 + tx] = sf(t[tx][ty + i * 8]);
}

__global__ __launch_bounds__(256)
void prep_mega(const float* __restrict__ wl, short* __restrict__ tab,
               const float* __restrict__ qkvw, short* __restrict__ qkvwT,
               const float* __restrict__ faow, short* __restrict__ faowT,
               const float* __restrict__ caqw, short* __restrict__ caqwT,
               const float* __restrict__ cakw, short* __restrict__ cakwT,
               const float* __restrict__ cavw, short* __restrict__ cavwT,
               const float* __restrict__ caow, short* __restrict__ caowT,
               const float* __restrict__ ctx, short* __restrict__ ctxb)
{
    __shared__ float tls[32][33];
    int bid = blockIdx.x, tid = threadIdx.x;
    if (bid < 16) {
        int idx = bid * 256 + tid;
        if (idx < 3969) {
            int i = idx / 63, j = idx - i * 63;
            float dy = (float)(i - 31), dx = (float)(j - 31);
            float dist = sqrtf(dy * dy + dx * dx + 1e-8f);
            float den = fabsf(wl[0]) * 32.0f + 1e-6f;
            tab[idx] = sf(0.1f * cosf(6.283185307179586f * dist / den) * 1.4426950408889634f);
        }
        return;
    }
    bid -= 16;
    if (bid < 768) { wtile(qkvw, qkvwT, 512, 1536, bid, tid, tls); return; }
    bid -= 768;
    if (bid < 256) { wtile(faow, faowT, 512, 512, bid, tid, tls); return; }
    bid -= 256;
    if (bid < 256) { wtile(caqw, caqwT, 512, 512, bid, tid, tls); return; }
    bid -= 256;
    if (bid < 384) { wtile(cakw, cakwT, 768, 512, bid, tid, tls); return; }
    bid -= 384;
    if (bid < 384) { wtile(cavw, cavwT, 768, 512, bid, tid, tls); return; }
    bid -= 384;
    if (bid < 256) { wtile(caow, caowT, 512, 512, bid, tid, tls); return; }
    bid -= 256;
    // ctx convert: 231 blocks x 1024 elems
    int base = bid * 1024 + tid * 4;
    float4 v = *(const float4*)(ctx + base);
    s4v o; o[0] = sf(v.x); o[1] = sf(v.y); o[2] = sf(v.z); o[3] = sf(v.w);
    *(s4v*)(ctxb + base) = o;
}

// ---------------------------------------------------------------------------
// fused GroupNorm + transpose: reads src fp32 [b][512][1024] ([c][n]),
// writes dst bf16 [b][1024][512] ([n][c]). One block per (group, batch).
// ---------------------------------------------------------------------------
__global__ __launch_bounds__(256)
void gn_fused(const float* __restrict__ src, const float* __restrict__ w,
              const float* __restrict__ bs, short* __restrict__ dst)
{
    int g = blockIdx.x, b = blockIdx.y;
    const float* xb = src + ((size_t)b * 512 + g * 16) * 1024;
    float s = 0.f, ss = 0.f;
    for (int l = threadIdx.x; l < 4096; l += 256) {
        float4 v = *(const float4*)(xb + l * 4);
        s += v.x + v.y + v.z + v.w;
        ss += v.x * v.x + v.y * v.y + v.z * v.z + v.w * v.w;
    }
    for (int off = 32; off; off >>= 1) {
        s  += __shfl_down(s,  off);
        ss += __shfl_down(ss, off);
    }
    __shared__ float sred[8], ssred[8];
    int wid = threadIdx.x >> 6;
    if ((threadIdx.x & 63) == 0) { sred[wid] = s; ssred[wid] = ss; }
    __syncthreads();
    if (threadIdx.x == 0) {
        float S = 0.f, SS = 0.f;
        for (int i = 0; i < 4; ++i) { S += sred[i]; SS += ssred[i]; }
        float mu = S * (1.f / 16384.f);
        float var = SS * (1.f / 16384.f) - mu * mu;
        sred[4] = mu; ssred[4] = rsqrtf(var + 1e-5f);
    }
    __syncthreads();
    float mu = sred[4], rs = ssred[4];

    int c4 = threadIdx.x & 3, nb = threadIdx.x >> 2;
    int c = g * 16 + c4 * 4;
    float4 wv = *(const float4*)(w + c);
    float4 bv = *(const float4*)(bs + c);
    for (int rep = 0; rep < 16; ++rep) {
        int n = rep * 64 + nb;
        float v0 = xb[(size_t)(c4 * 4 + 0) * 1024 + n];
        float v1 = xb[(size_t)(c4 * 4 + 1) * 1024 + n];
        float v2 = xb[(size_t)(c4 * 4 + 2) * 1024 + n];
        float v3 = xb[(size_t)(c4 * 4 + 3) * 1024 + n];
        s4v hb;
        hb[0] = sf((v0 - mu) * rs * wv.x + bv.x);
        hb[1] = sf((v1 - mu) * rs * wv.y + bv.y);
        hb[2] = sf((v2 - mu) * rs * wv.z + bv.z);
        hb[3] = sf((v3 - mu) * rs * wv.w + bv.w);
        *(s4v*)(dst + ((size_t)b * 1024 + n) * 512 + c) = hb;
    }
}

// ---------------------------------------------------------------------------
// MFMA GEMM, double-buffered LDS, one barrier per K-step.
// out[b][m][j] = sum_k A[b][m][k] * Wt[b][j][k]
// EPI 0: bf16 store [m][J].
// EPI 1: fp32 store [m][J] + bias[m] + res[b][m][j]   (transposed-result GEMMs)
// EPI 3: qkv: j<1024 -> bf16 store stride 1024 into outv; j>=1024 -> V
//        transposed into out2v (Vg [b][512][1024], row = j-1024, col = m)
// EPI 4: kv:  j<512  -> bf16 store stride 512 into outv (guard m<M);
//        j>=512 -> V transposed into out2v (v2t [b][512][80], row = j-512,
//        col = m, guarded to col<80; rows m>=M have acc==0 -> zero fill)
// ---------------------------------------------------------------------------
template<int EPI>
__global__ __launch_bounds__(256)
void gemm_mfma(const short* __restrict__ A, const short* __restrict__ Wt,
               const float* __restrict__ bias, const float* __restrict__ res,
               void* __restrict__ outv, void* __restrict__ out2v,
               int M, int K, int J,
               long aStride, long wStride, long oStride, long o2Stride)
{
    int j0 = blockIdx.x * 128, m0 = blockIdx.y * 128, b = blockIdx.z;
    __shared__ short As[2][128][40];
    __shared__ short Ws[2][128][40];
    int tid = threadIdx.x, w = tid >> 6, lane = tid & 63;
    int lr = lane & 15, lg = lane >> 4;
    int wr = w >> 1, wc = w & 1;
    const short* Ab  = A  + (size_t)b * aStride;
    const short* Wtb = Wt + (size_t)b * wStride;
    int r0 = tid >> 2, c0 = (tid & 3) * 8;
    int r1 = 64 + r0;
    bool gA0 = (m0 + r0) < M, gA1 = (m0 + r1) < M;
    const short* ap0 = Ab + (size_t)(m0 + r0) * K + c0;
    const short* ap1 = Ab + (size_t)(m0 + r1) * K + c0;
    const short* wp0 = Wtb + (size_t)(j0 + r0) * K + c0;
    const short* wp1 = Wtb + (size_t)(j0 + r1) * K + c0;

    f4 acc[4][4];
#pragma unroll
    for (int i = 0; i < 4; ++i)
#pragma unroll
        for (int j = 0; j < 4; ++j) acc[i][j] = zerof4();

    *(bf8*)&As[0][r0][c0] = gA0 ? *(const bf8*)ap0 : zero8();
    *(bf8*)&As[0][r1][c0] = gA1 ? *(const bf8*)ap1 : zero8();
    *(bf8*)&Ws[0][r0][c0] = *(const bf8*)wp0;
    *(bf8*)&Ws[0][r1][c0] = *(const bf8*)wp1;
    __syncthreads();

    int nk = K >> 5;
    for (int t = 0; t < nk; ++t) {
        int cur = t & 1;
        bool more = (t + 1) < nk;
        bf8 na0, na1, nw0, nw1;
        if (more) {
            int ko = (t + 1) << 5;
            na0 = gA0 ? *(const bf8*)(ap0 + ko) : zero8();
            na1 = gA1 ? *(const bf8*)(ap1 + ko) : zero8();
            nw0 = *(const bf8*)(wp0 + ko);
            nw1 = *(const bf8*)(wp1 + ko);
        }
        bf8 af[4], bfr[4];
#pragma unroll
        for (int fi = 0; fi < 4; ++fi)
            af[fi] = *(const bf8*)&As[cur][wr * 64 + fi * 16 + lr][lg * 8];
#pragma unroll
        for (int fj = 0; fj < 4; ++fj)
            bfr[fj] = *(const bf8*)&Ws[cur][wc * 64 + fj * 16 + lr][lg * 8];
#pragma unroll
        for (int fi = 0; fi < 4; ++fi)
#pragma unroll
            for (int fj = 0; fj < 4; ++fj)
                acc[fi][fj] = MFMA(af[fi], bfr[fj], acc[fi][fj]);
        if (more) {
            int nb = cur ^ 1;
            *(bf8*)&As[nb][r0][c0] = na0;
            *(bf8*)&As[nb][r1][c0] = na1;
            *(bf8*)&Ws[nb][r0][c0] = nw0;
            *(bf8*)&Ws[nb][r1][c0] = nw1;
        }
        __syncthreads();
    }

    if (EPI == 0) {
        short* out = (short*)outv + (size_t)b * oStride;
#pragma unroll
        for (int fi = 0; fi < 4; ++fi)
#pragma unroll
            for (int reg = 0; reg < 4; ++reg) {
                int m = m0 + wr * 64 + fi * 16 + lg * 4 + reg;
                if (m < M) {
#pragma unroll
                    for (int fj = 0; fj < 4; ++fj)
                        out[(size_t)m * J + j0 + wc * 64 + fj * 16 + lr] = sf(acc[fi][fj][reg]);
                }
            }
    } else if (EPI == 1) {
        float* out = (float*)outv + (size_t)b * oStride;
        const float* rp = res + (size_t)b * oStride;
#pragma unroll
        for (int fi = 0; fi < 4; ++fi) {
            float4 bq = *(const float4*)(bias + m0 + wr * 64 + fi * 16 + lg * 4);
            float bvr[4] = {bq.x, bq.y, bq.z, bq.w};
#pragma unroll
            for (int reg = 0; reg < 4; ++reg) {
                int m = m0 + wr * 64 + fi * 16 + lg * 4 + reg;
                size_t ro = (size_t)m * J + j0 + wc * 64;
#pragma unroll
                for (int fj = 0; fj < 4; ++fj) {
                    size_t idx = ro + fj * 16 + lr;
                    out[idx] = acc[fi][fj][reg] + bvr[reg] + rp[idx];
                }
            }
        }
    } else if (EPI == 3) {
        if (j0 < 1024) {
            short* out = (short*)outv + (size_t)b * oStride;
#pragma unroll
            for (int fi = 0; fi < 4; ++fi)
#pragma unroll
                for (int reg = 0; reg < 4; ++reg) {
                    int m = m0 + wr * 64 + fi * 16 + lg * 4 + reg;
#pragma unroll
                    for (int fj = 0; fj < 4; ++fj)
                        out[(size_t)m * 1024 + j0 + wc * 64 + fj * 16 + lr] = sf(acc[fi][fj][reg]);
                }
        } else {
            short* Vg = (short*)out2v + (size_t)b * o2Stride;
#pragma unroll
            for (int fi = 0; fi < 4; ++fi) {
                int n = m0 + wr * 64 + fi * 16 + lg * 4;
#pragma unroll
                for (int fj = 0; fj < 4; ++fj) {
                    int dg = j0 - 1024 + wc * 64 + fj * 16 + lr;
                    s4v v;
#pragma unroll
                    for (int reg = 0; reg < 4; ++reg) v[reg] = sf(acc[fi][fj][reg]);
                    *(s4v*)(Vg + (size_t)dg * 1024 + n) = v;
                }
            }
        }
    } else {  // EPI == 4
        if (j0 < 512) {
            short* out = (short*)outv + (size_t)b * oStride;
#pragma unroll
            for (int fi = 0; fi < 4; ++fi)
#pragma unroll
                for (int reg = 0; reg < 4; ++reg) {
                    int m = m0 + wr * 64 + fi * 16 + lg * 4 + reg;
                    if (m < M) {
#pragma unroll
                        for (int fj = 0; fj < 4; ++fj)
                            out[(size_t)m * 512 + j0 + wc * 64 + fj * 16 + lr] = sf(acc[fi][fj][reg]);
                    }
                }
        } else {
            short* vt = (short*)out2v + (size_t)b * o2Stride;
#pragma unroll
            for (int fi = 0; fi < 4; ++fi) {
                int l0 = wr * 64 + fi * 16 + lg * 4;      // m0 == 0
                if (l0 < 80) {
#pragma unroll
                    for (int fj = 0; fj < 4; ++fj) {
                        int dg = j0 - 512 + wc * 64 + fj * 16 + lr;
                        s4v v;
#pragma unroll
                        for (int reg = 0; reg < 4; ++reg) v[reg] = sf(acc[fi][fj][reg]);
                        *(s4v*)(vt + (size_t)dg * 80 + l0) = v;
                    }
                }
            }
        }
    }
}

// ---------------------------------------------------------------------------
// Fresnel attention v2: swapped QK^T (lane owns one query), in-lane softmax,
// double-buffered swizzled K/V LDS, one barrier per 64-key tile.
// qkb: [b][n][1024] (q at 0, k at 512); Vg: [b][512][1024] row=h*64+d
// ---------------------------------------------------------------------------
__global__ __launch_bounds__(256)
void fresnel_attn_v2(const short* __restrict__ qkb, const short* __restrict__ Vg,
                     const short* __restrict__ tab, short* __restrict__ ao)
{
    int qb = blockIdx.x, h = blockIdx.y, b = blockIdx.z;
    int n0 = qb * 64;
    __shared__ short Ks[2][64][64];
    __shared__ short Vt[2][64][64];
    __shared__ short Ps[4][16][72];
    __shared__ short tabs[4032];
    int tid = threadIdx.x, w = tid >> 6, lane = tid & 63;
    int lr = lane & 15, lg = lane >> 4;
    const short* qp = qkb + (size_t)b * 1048576;
    const short* vp = Vg + ((size_t)b * 512 + h * 64) * 1024;

    for (int l = tid; l < 504; l += 256)
        *(bf8*)&tabs[l * 8] = *(const bf8*)(tab + l * 8);

    int q = n0 + w * 16 + lr;                 // this lane's query row
    bf8 qf0 = *(const bf8*)(qp + (size_t)q * 1024 + h * 64 + lg * 8);
    bf8 qf1 = *(const bf8*)(qp + (size_t)q * 1024 + h * 64 + 32 + lg * 8);

    // staging: 512 chunks (64 rows x 8), 2 K + 2 V chunks per thread
    int sr0 = tid >> 3, sc0 = tid & 7;
    int sr1 = 32 + sr0;
    int sw0 = ((sc0 ^ (sr0 & 7))) * 8;
    int sw1 = ((sc0 ^ (sr1 & 7))) * 8;

    *(bf8*)&Ks[0][sr0][sw0] = *(const bf8*)(qp + (size_t)sr0 * 1024 + 512 + h * 64 + sc0 * 8);
    *(bf8*)&Ks[0][sr1][sw1] = *(const bf8*)(qp + (size_t)sr1 * 1024 + 512 + h * 64 + sc0 * 8);
    *(bf8*)&Vt[0][sr0][sw0] = *(const bf8*)(vp + (size_t)sr0 * 1024 + sc0 * 8);
    *(bf8*)&Vt[0][sr1][sw1] = *(const bf8*)(vp + (size_t)sr1 * 1024 + sc0 * 8);
    __syncthreads();

    float mrun = -1e30f, lrun = 0.f;          // log2 domain
    f4 o[4];
#pragma unroll
    for (int i = 0; i < 4; ++i) o[i] = zerof4();

    int ybase = (q >> 5) + 31;
    int xbase = (q & 31) + 31 - lg * 4;
    int rsw = lr & 7;
    int rc0 = (lg ^ rsw) * 8;                 // kc=0 swizzled chunk offset
    int rc1 = ((4 + lg) ^ rsw) * 8;           // kc=1

    for (int t = 0; t < 16; ++t) {
        int cur = t & 1;
        int m0 = t << 6;
        bool more = t < 15;
        bf8 nk0, nk1, nv0, nv1;
        if (more) {
            int m1 = m0 + 64;
            nk0 = *(const bf8*)(qp + (size_t)(m1 + sr0) * 1024 + 512 + h * 64 + sc0 * 8);
            nk1 = *(const bf8*)(qp + (size_t)(m1 + sr1) * 1024 + 512 + h * 64 + sc0 * 8);
            nv0 = *(const bf8*)(vp + (size_t)sr0 * 1024 + m1 + sc0 * 8);
            nv1 = *(const bf8*)(vp + (size_t)sr1 * 1024 + m1 + sc0 * 8);
        }

        // QK^T swapped: D[key][query], lane holds query lr, keys fj*16+lg*4+reg
        f4 sa[4];
#pragma unroll
        for (int fj = 0; fj < 4; ++fj) sa[fj] = zerof4();
#pragma unroll
        for (int fj = 0; fj < 4; ++fj)
            sa[fj] = MFMA(*(const bf8*)&Ks[cur][fj * 16 + lr][rc0], qf0, sa[fj]);
#pragma unroll
        for (int fj = 0; fj < 4; ++fj)
            sa[fj] = MFMA(*(const bf8*)&Ks[cur][fj * 16 + lr][rc1], qf1, sa[fj]);

        // scores in log2 domain + interference
        int yb = ybase - (m0 >> 5);
        float pv[4][4];
        float tmax = -1e30f;
#pragma unroll
        for (int fj = 0; fj < 4; ++fj) {
            int rowoff = (yb - (fj >> 1)) * 63 + xbase - (fj & 1) * 16;
#pragma unroll
            for (int reg = 0; reg < 4; ++reg) {
                float t2 = fmaf(sa[fj][reg], 0.18033688011112042f, fs(tabs[rowoff - reg]));
                pv[fj][reg] = t2;
                tmax = fmaxf(tmax, t2);
            }
        }
        tmax = fmaxf(tmax, __shfl_xor(tmax, 16));
        tmax = fmaxf(tmax, __shfl_xor(tmax, 32));
        float mnew = fmaxf(mrun, tmax);
        float rsc = EXP2(mrun - mnew);
        mrun = mnew;
        float psum = 0.f;
#pragma unroll
        for (int fj = 0; fj < 4; ++fj) {
            s4v pw;
#pragma unroll
            for (int reg = 0; reg < 4; ++reg) {
                float p = EXP2(pv[fj][reg] - mnew);
                psum += p;
                pw[reg] = sf(p);
            }
            *(s4v*)&Ps[w][lr][fj * 16 + lg * 4] = pw;   // row = query lr
        }
        psum += __shfl_xor(psum, 16);
        psum += __shfl_xor(psum, 32);
        lrun = lrun * rsc + psum;
#pragma unroll
        for (int fd = 0; fd < 4; ++fd)
#pragma unroll
            for (int reg = 0; reg < 4; ++reg) o[fd][reg] *= rsc;

        // PV: O^T[d][q] = mfma(Vt rows=d, P cols=q)
        bf8 pa0 = *(const bf8*)&Ps[w][lr][lg * 8];
        bf8 pa1 = *(const bf8*)&Ps[w][lr][32 + lg * 8];
#pragma unroll
        for (int fd = 0; fd < 4; ++fd) {
            o[fd] = MFMA(*(const bf8*)&Vt[cur][fd * 16 + lr][rc0], pa0, o[fd]);
            o[fd] = MFMA(*(const bf8*)&Vt[cur][fd * 16 + lr][rc1], pa1, o[fd]);
        }

        if (more) {
            int nb = cur ^ 1;
            *(bf8*)&Ks[nb][sr0][sw0] = nk0;
            *(bf8*)&Ks[nb][sr1][sw1] = nk1;
            *(bf8*)&Vt[nb][sr0][sw0] = nv0;
            *(bf8*)&Vt[nb][sr1][sw1] = nv1;
        }
        __syncthreads();
    }

    float inv = 1.f / lrun;
    size_t rb = ((size_t)b * N_ + q) * 512 + h * 64;
#pragma unroll
    for (int fd = 0; fd < 4; ++fd) {
        s4v ov;
#pragma unroll
        for (int reg = 0; reg < 4; ++reg) ov[reg] = sf(o[fd][reg] * inv);
        *(s4v*)(ao + rb + fd * 16 + lg * 4) = ov;
    }
}

// ---------------------------------------------------------------------------
// Cross attention, bf16 MFMA, single K-tile (L=77 padded to 96).
// q2: [b][1024][512]; k2: [b][77][512]; v2t: [b][512][80] row=h*64+d
// ---------------------------------------------------------------------------
__global__ __launch_bounds__(256)
void cross_attn_mfma(const short* __restrict__ q2, const short* __restrict__ k2,
                     const short* __restrict__ v2t, short* __restrict__ ao2)
{
    int qb = blockIdx.x, h = blockIdx.y, b = blockIdx.z;
    int n0 = qb * 64;
    __shared__ short Qs[64][72], Ks[96][72], Vt[64][104];
    __shared__ short Ps[4][16][104];
    int tid = threadIdx.x, w = tid >> 6, lane = tid & 63;
    int lr = lane & 15, lg = lane >> 4;

    for (int l = tid; l < 512; l += 256) {
        int n = l >> 3, dq = l & 7;
        *(bf8*)&Qs[n][dq * 8] = *(const bf8*)(q2 + ((size_t)b * N_ + n0 + n) * 512 + h * 64 + dq * 8);
    }
    for (int l = tid; l < 768; l += 256) {
        int m = l >> 3, dq = l & 7;
        bf8 v = zero8();
        if (m < L_) v = *(const bf8*)(k2 + ((size_t)b * L_ + m) * 512 + h * 64 + dq * 8);
        *(bf8*)&Ks[m][dq * 8] = v;
    }
    for (int l = tid; l < 768; l += 256) {
        int d = l / 12, cq = l % 12;
        bf8 v = zero8();
        if (cq < 10) v = *(const bf8*)(v2t + ((size_t)b * 512 + h * 64 + d) * 80 + cq * 8);
        *(bf8*)&Vt[d][cq * 8] = v;
    }
    __syncthreads();

    f4 sacc[6];
#pragma unroll
    for (int fj = 0; fj < 6; ++fj) sacc[fj] = zerof4();
#pragma unroll
    for (int kc = 0; kc < 2; ++kc) {
        bf8 aq = *(const bf8*)&Qs[w * 16 + lr][kc * 32 + lg * 8];
#pragma unroll
        for (int fj = 0; fj < 6; ++fj)
            sacc[fj] = MFMA(aq, *(const bf8*)&Ks[fj * 16 + lr][kc * 32 + lg * 8], sacc[fj]);
    }

    float rinv[4];
#pragma unroll
    for (int reg = 0; reg < 4; ++reg) {
        float sv[6];
#pragma unroll
        for (int fj = 0; fj < 6; ++fj) {
            int m = fj * 16 + lr;
            sv[fj] = (m < L_) ? sacc[fj][reg] * 0.125f : -30000.f;
        }
        float mx = sv[0];
#pragma unroll
        for (int fj = 1; fj < 6; ++fj) mx = fmaxf(mx, sv[fj]);
#pragma unroll
        for (int off = 1; off < 16; off <<= 1) mx = fmaxf(mx, __shfl_xor(mx, off));
        float psum = 0.f;
#pragma unroll
        for (int fj = 0; fj < 6; ++fj) {
            float p = __expf(sv[fj] - mx);
            psum += p;
            Ps[w][lg * 4 + reg][fj * 16 + lr] = sf(p);
        }
#pragma unroll
        for (int off = 1; off < 16; off <<= 1) psum += __shfl_xor(psum, off);
        rinv[reg] = 1.f / psum;
    }
    __syncthreads();

    f4 o[4];
#pragma unroll
    for (int fd = 0; fd < 4; ++fd) o[fd] = zerof4();
#pragma unroll
    for (int kc = 0; kc < 3; ++kc) {
        bf8 ap = *(const bf8*)&Ps[w][lr][kc * 32 + lg * 8];
#pragma unroll
        for (int fd = 0; fd < 4; ++fd)
            o[fd] = MFMA(ap, *(const bf8*)&Vt[fd * 16 + lr][kc * 32 + lg * 8], o[fd]);
    }

#pragma unroll
    for (int reg = 0; reg < 4; ++reg) {
        size_t rb = ((size_t)b * N_ + n0 + w * 16 + lg * 4 + reg) * 512 + h * 64;
#pragma unroll
        for (int fd = 0; fd < 4; ++fd)
            ao2[rb + fd * 16 + lr] = sf(o[fd][reg] * rinv[reg]);
    }
}

// ---------------------------------------------------------------------------
extern "C" void kernel_launch(void* const* d_in, const int* in_sizes, int n_in,
                              void* d_out, int out_size, void* d_ws, size_t ws_size,
                              hipStream_t stream)
{
    const float* x    = (const float*)d_in[0];
    const float* ctx  = (const float*)d_in[1];
    const float* gn1w = (const float*)d_in[2];
    const float* gn1b = (const float*)d_in[3];
    const float* gn2w = (const float*)d_in[4];
    const float* gn2b = (const float*)d_in[5];
    const float* qkvw = (const float*)d_in[6];
    const float* faow = (const float*)d_in[7];
    const float* faob = (const float*)d_in[8];
    const float* wl   = (const float*)d_in[9];
    const float* caqw = (const float*)d_in[10];
    const float* cakw = (const float*)d_in[11];
    const float* cavw = (const float*)d_in[12];
    const float* caow = (const float*)d_in[13];
    const float* caob = (const float*)d_in[14];
    float* out = (float*)d_out;
    char* ws = (char*)d_ws;

    float* x1    = (float*)(ws + 0);            // 8 MB fp32 [b][c][n]
    short* qkb   = (short*)(ws + 8388608);      // 8 MB bf16 [b][n][1024] (q|k)
    short* Vg    = (short*)(ws + 16777216);     // 4 MB bf16 [b][512][1024]
    short* h1b   = (short*)(ws + 20971520);     // 4 MB [b][n][512] (h1 / h2)
    short* ao    = (short*)(ws + 25165824);     // 4 MB [b][n][512] (ao / ao2)
    short* q2b   = (short*)(ws + 29360128);     // 4 MB
    short* qkvwT = (short*)(ws + 33554432);     // 1.5 MB  [1536][512]
    short* faowT = (short*)(ws + 35127296);     // 0.5 MB  [512][512]
    short* caqwT = (short*)(ws + 35651584);     // 0.5 MB
    short* cakwT = (short*)(ws + 36175872);     // 0.75 MB [512][768]
    short* cavwT = (short*)(ws + 36962304);     // 0.75 MB (contiguous after cakwT)
    short* caowT = (short*)(ws + 37748736);     // 0.5 MB
    short* k2b   = (short*)(ws + 38273024);     // 308 KB [b][77][512]
    short* v2t   = (short*)(ws + 38588416);     // 320 KB [b][512][80]
    short* ctxb  = (short*)(ws + 38916096);     // 462 KB
    short* tab   = (short*)(ws + 39389184);     // 8 KB

    prep_mega<<<2551, 256, 0, stream>>>(wl, tab, qkvw, qkvwT, faow, faowT,
                                        caqw, caqwT, cakw, cakwT, cavw, cavwT,
                                        caow, caowT, ctx, ctxb);
    // h1 = GroupNorm1(x), transposed to [n][c] bf16
    gn_fused<<<dim3(32, 4), 256, 0, stream>>>(x, gn1w, gn1b, h1b);
    // qkv = h1 @ qkv_w : M=1024 K=512 J=1536; q|k -> qkb, v -> Vg (transposed)
    gemm_mfma<3><<<dim3(12, 8, 4), 256, 0, stream>>>(
        h1b, qkvwT, nullptr, nullptr, qkb, Vg, 1024, 512, 1536,
        524288L, 0L, 1048576L, 524288L);
    fresnel_attn_v2<<<dim3(16, 8, 4), 256, 0, stream>>>(qkb, Vg, tab, ao);
    // x1[c][n] = x[c][n] + (ao @ fa_out_w)^T + fa_out_b[c]   (transposed GEMM)
    gemm_mfma<1><<<dim3(8, 4, 4), 256, 0, stream>>>(
        faowT, ao, faob, x, x1, nullptr, 512, 512, 1024,
        0L, 524288L, 524288L, 0L);
    // h2 = GroupNorm2(x1), transposed to [n][c] bf16
    gn_fused<<<dim3(32, 4), 256, 0, stream>>>(x1, gn2w, gn2b, h1b);
    // q2 = h2 @ ca_q_w : M=1024 K=512 J=512
    gemm_mfma<0><<<dim3(4, 8, 4), 256, 0, stream>>>(
        h1b, caqwT, nullptr, nullptr, q2b, nullptr, 1024, 512, 512,
        524288L, 0L, 524288L, 0L);
    // k2|v2 = ctx @ [ca_k_w | ca_v_w] : M=77 K=768 J=1024; k -> k2b, v -> v2t
    gemm_mfma<4><<<dim3(8, 1, 4), 256, 0, stream>>>(
        ctxb, cakwT, nullptr, nullptr, k2b, v2t, 77, 768, 1024,
        59136L, 0L, 39424L, 40960L);
    cross_attn_mfma<<<dim3(16, 8, 4), 256, 0, stream>>>(q2b, k2b, v2t, ao);
    // out[c][n] = x1[c][n] + (ao2 @ ca_out_w)^T + ca_out_b[c]  (direct to d_out)
    gemm_mfma<1><<<dim3(8, 4, 4), 256, 0, stream>>>(
        caowT, ao, caob, x1, out, nullptr, 512, 512, 1024,
        0L, 524288L, 524288L, 0L);
}

// Round 5
// 218.906 us; speedup vs baseline: 4.4634x; 1.0199x over previous
//
#include <hip/hip_runtime.h>
#include <hip/hip_bf16.h>
#include <math.h>

#define B_    4
#define N_    1024
#define L_    77

typedef float f4 __attribute__((ext_vector_type(4)));
typedef short bf8 __attribute__((ext_vector_type(8)));
typedef short s4v __attribute__((ext_vector_type(4)));

#if __has_builtin(__builtin_amdgcn_exp2f)
#define EXP2(x) __builtin_amdgcn_exp2f(x)
#else
#define EXP2(x) exp2f(x)
#endif

__device__ __forceinline__ float fs(short s) {
    unsigned u = ((unsigned)(unsigned short)s) << 16;
    return __builtin_bit_cast(float, u);
}
__device__ __forceinline__ short sf(float f) {
    unsigned u = __builtin_bit_cast(unsigned, f);
    unsigned r = (u + 0x7FFF + ((u >> 16) & 1)) >> 16;
    return (short)r;
}
__device__ __forceinline__ bf8 zero8() { bf8 v; for (int i = 0; i < 8; ++i) v[i] = 0; return v; }
__device__ __forceinline__ f4 zerof4() { f4 v; for (int i = 0; i < 4; ++i) v[i] = 0.f; return v; }

#define MFMA(a, b, c) __builtin_amdgcn_mfma_f32_16x16x32_bf16((a), (b), (c), 0, 0, 0)

// ---------------------------------------------------------------------------
// GroupNorm body: reads src fp32 [b][512][1024] ([c][n]), writes dst bf16
// [b][1024][512] ([n][c]). One call per (group, batch) block.
// ---------------------------------------------------------------------------
__device__ __forceinline__ void gn_body(const float* __restrict__ src,
                                        const float* __restrict__ w,
                                        const float* __restrict__ bs,
                                        short* __restrict__ dst, int g, int b)
{
    const float* xb = src + ((size_t)b * 512 + g * 16) * 1024;
    float s = 0.f, ss = 0.f;
    for (int l = threadIdx.x; l < 4096; l += 256) {
        float4 v = *(const float4*)(xb + l * 4);
        s += v.x + v.y + v.z + v.w;
        ss += v.x * v.x + v.y * v.y + v.z * v.z + v.w * v.w;
    }
    for (int off = 32; off; off >>= 1) {
        s  += __shfl_down(s,  off);
        ss += __shfl_down(ss, off);
    }
    __shared__ float sred[8], ssred[8];
    int wid = threadIdx.x >> 6;
    if ((threadIdx.x & 63) == 0) { sred[wid] = s; ssred[wid] = ss; }
    __syncthreads();
    if (threadIdx.x == 0) {
        float S = 0.f, SS = 0.f;
        for (int i = 0; i < 4; ++i) { S += sred[i]; SS += ssred[i]; }
        float mu = S * (1.f / 16384.f);
        float var = SS * (1.f / 16384.f) - mu * mu;
        sred[4] = mu; ssred[4] = rsqrtf(var + 1e-5f);
    }
    __syncthreads();
    float mu = sred[4], rs = ssred[4];

    int c4 = threadIdx.x & 3, nb = threadIdx.x >> 2;
    int c = g * 16 + c4 * 4;
    float4 wv = *(const float4*)(w + c);
    float4 bv = *(const float4*)(bs + c);
    for (int rep = 0; rep < 16; ++rep) {
        int n = rep * 64 + nb;
        float v0 = xb[(size_t)(c4 * 4 + 0) * 1024 + n];
        float v1 = xb[(size_t)(c4 * 4 + 1) * 1024 + n];
        float v2 = xb[(size_t)(c4 * 4 + 2) * 1024 + n];
        float v3 = xb[(size_t)(c4 * 4 + 3) * 1024 + n];
        s4v hb;
        hb[0] = sf((v0 - mu) * rs * wv.x + bv.x);
        hb[1] = sf((v1 - mu) * rs * wv.y + bv.y);
        hb[2] = sf((v2 - mu) * rs * wv.z + bv.z);
        hb[3] = sf((v3 - mu) * rs * wv.w + bv.w);
        *(s4v*)(dst + ((size_t)b * 1024 + n) * 512 + c) = hb;
    }
}

// ---------------------------------------------------------------------------
// prep mega-kernel: gn1 + tab (pre-scaled by log2e) + 6 weight transposes +
// ctx->bf16.  Blocks: [0,128) gn1 | [128,144) tab | [144,2448) wtiles |
// [2448,2679) ctx convert.
// ---------------------------------------------------------------------------
__device__ __forceinline__ void wtile(const float* __restrict__ in, short* __restrict__ out,
                                      int K, int J, int tile, int tid, float (*t)[33])
{
    int jt = J >> 5;
    int j0 = (tile % jt) * 32, k0 = (tile / jt) * 32;
    int tx = tid & 31, ty = tid >> 5;
#pragma unroll
    for (int i = 0; i < 4; ++i)
        t[ty + i * 8][tx] = in[(size_t)(k0 + ty + i * 8) * J + j0 + tx];
    __syncthreads();
#pragma unroll
    for (int i = 0; i < 4; ++i)
        out[(size_t)(j0 + ty + i * 8) * K + k0 + tx] = sf(t[tx][ty + i * 8]);
}

__global__ __launch_bounds__(256)
void prep_mega(const float* __restrict__ x, const float* __restrict__ gn1w,
               const float* __restrict__ gn1b, short* __restrict__ h1b,
               const float* __restrict__ wl, short* __restrict__ tab,
               const float* __restrict__ qkvw, short* __restrict__ qkvwT,
               const float* __restrict__ faow, short* __restrict__ faowT,
               const float* __restrict__ caqw, short* __restrict__ caqwT,
               const float* __restrict__ cakw, short* __restrict__ cakwT,
               const float* __restrict__ cavw, short* __restrict__ cavwT,
               const float* __restrict__ caow, short* __restrict__ caowT,
               const float* __restrict__ ctx, short* __restrict__ ctxb)
{
    __shared__ float tls[32][33];
    int bid = blockIdx.x, tid = threadIdx.x;
    if (bid < 128) { gn_body(x, gn1w, gn1b, h1b, bid & 31, bid >> 5); return; }
    bid -= 128;
    if (bid < 16) {
        int idx = bid * 256 + tid;
        if (idx < 3969) {
            int i = idx / 63, j = idx - i * 63;
            float dy = (float)(i - 31), dx = (float)(j - 31);
            float dist = sqrtf(dy * dy + dx * dx + 1e-8f);
            float den = fabsf(wl[0]) * 32.0f + 1e-6f;
            tab[idx] = sf(0.1f * cosf(6.283185307179586f * dist / den) * 1.4426950408889634f);
        }
        return;
    }
    bid -= 16;
    if (bid < 768) { wtile(qkvw, qkvwT, 512, 1536, bid, tid, tls); return; }
    bid -= 768;
    if (bid < 256) { wtile(faow, faowT, 512, 512, bid, tid, tls); return; }
    bid -= 256;
    if (bid < 256) { wtile(caqw, caqwT, 512, 512, bid, tid, tls); return; }
    bid -= 256;
    if (bid < 384) { wtile(cakw, cakwT, 768, 512, bid, tid, tls); return; }
    bid -= 384;
    if (bid < 384) { wtile(cavw, cavwT, 768, 512, bid, tid, tls); return; }
    bid -= 384;
    if (bid < 256) { wtile(caow, caowT, 512, 512, bid, tid, tls); return; }
    bid -= 256;
    // ctx convert: 231 blocks x 1024 elems
    int base = bid * 1024 + tid * 4;
    float4 v = *(const float4*)(ctx + base);
    s4v o; o[0] = sf(v.x); o[1] = sf(v.y); o[2] = sf(v.z); o[3] = sf(v.w);
    *(s4v*)(ctxb + base) = o;
}

// ---------------------------------------------------------------------------
// gn2 standalone wrapper
// ---------------------------------------------------------------------------
__global__ __launch_bounds__(256)
void gn_kernel(const float* __restrict__ src, const float* __restrict__ w,
               const float* __restrict__ bs, short* __restrict__ dst)
{
    gn_body(src, w, bs, dst, blockIdx.x, blockIdx.y);
}

// ---------------------------------------------------------------------------
// MFMA GEMM body, double-buffered LDS, one barrier per K-step.
// out[b][m][j] = sum_k A[b][m][k] * Wt[b][j][k]
// EPI 0: bf16 store [m][J].
// EPI 1: fp32 store [m][J] + bias[m] + res[b][m][j]   (transposed-result GEMMs)
// EPI 3: qkv: j<1024 -> bf16 store stride 1024; j>=1024 -> V transposed into
//        out2v (Vg [b][512][1024], row = j-1024, col = m)
// EPI 4: kv:  j<512  -> bf16 store stride 512 (guard m<M); j>=512 -> V
//        transposed into out2v (v2t [b][512][80], col<80 guard)
// As/Ws: 2*128*40 shorts each (passed from wrapper's LDS).
// ---------------------------------------------------------------------------
template<int EPI>
__device__ __forceinline__ void gemm_body(
    short* As, short* Ws, int j0, int m0, int b,
    const short* __restrict__ A, const short* __restrict__ Wt,
    const float* __restrict__ bias, const float* __restrict__ res,
    void* __restrict__ outv, void* __restrict__ out2v,
    int M, int K, int J, long aStride, long wStride, long oStride, long o2Stride)
{
    int tid = threadIdx.x, w = tid >> 6, lane = tid & 63;
    int lr = lane & 15, lg = lane >> 4;
    int wr = w >> 1, wc = w & 1;
    const short* Ab  = A  + (size_t)b * aStride;
    const short* Wtb = Wt + (size_t)b * wStride;
    int r0 = tid >> 2, c0 = (tid & 3) * 8;
    int r1 = 64 + r0;
    bool gA0 = (m0 + r0) < M, gA1 = (m0 + r1) < M;
    const short* ap0 = Ab + (size_t)(m0 + r0) * K + c0;
    const short* ap1 = Ab + (size_t)(m0 + r1) * K + c0;
    const short* wp0 = Wtb + (size_t)(j0 + r0) * K + c0;
    const short* wp1 = Wtb + (size_t)(j0 + r1) * K + c0;

    f4 acc[4][4];
#pragma unroll
    for (int i = 0; i < 4; ++i)
#pragma unroll
        for (int j = 0; j < 4; ++j) acc[i][j] = zerof4();

    *(bf8*)(As + r0 * 40 + c0) = gA0 ? *(const bf8*)ap0 : zero8();
    *(bf8*)(As + r1 * 40 + c0) = gA1 ? *(const bf8*)ap1 : zero8();
    *(bf8*)(Ws + r0 * 40 + c0) = *(const bf8*)wp0;
    *(bf8*)(Ws + r1 * 40 + c0) = *(const bf8*)wp1;
    __syncthreads();

    int nk = K >> 5;
    for (int t = 0; t < nk; ++t) {
        int cur = (t & 1) * 5120;
        bool more = (t + 1) < nk;
        bf8 na0, na1, nw0, nw1;
        if (more) {
            int ko = (t + 1) << 5;
            na0 = gA0 ? *(const bf8*)(ap0 + ko) : zero8();
            na1 = gA1 ? *(const bf8*)(ap1 + ko) : zero8();
            nw0 = *(const bf8*)(wp0 + ko);
            nw1 = *(const bf8*)(wp1 + ko);
        }
        bf8 af[4], bfr[4];
#pragma unroll
        for (int fi = 0; fi < 4; ++fi)
            af[fi] = *(const bf8*)(As + cur + (wr * 64 + fi * 16 + lr) * 40 + lg * 8);
#pragma unroll
        for (int fj = 0; fj < 4; ++fj)
            bfr[fj] = *(const bf8*)(Ws + cur + (wc * 64 + fj * 16 + lr) * 40 + lg * 8);
#pragma unroll
        for (int fi = 0; fi < 4; ++fi)
#pragma unroll
            for (int fj = 0; fj < 4; ++fj)
                acc[fi][fj] = MFMA(af[fi], bfr[fj], acc[fi][fj]);
        if (more) {
            int nb = 5120 - cur;
            *(bf8*)(As + nb + r0 * 40 + c0) = na0;
            *(bf8*)(As + nb + r1 * 40 + c0) = na1;
            *(bf8*)(Ws + nb + r0 * 40 + c0) = nw0;
            *(bf8*)(Ws + nb + r1 * 40 + c0) = nw1;
        }
        __syncthreads();
    }

    if (EPI == 0) {
        short* out = (short*)outv + (size_t)b * oStride;
#pragma unroll
        for (int fi = 0; fi < 4; ++fi)
#pragma unroll
            for (int reg = 0; reg < 4; ++reg) {
                int m = m0 + wr * 64 + fi * 16 + lg * 4 + reg;
                if (m < M) {
#pragma unroll
                    for (int fj = 0; fj < 4; ++fj)
                        out[(size_t)m * J + j0 + wc * 64 + fj * 16 + lr] = sf(acc[fi][fj][reg]);
                }
            }
    } else if (EPI == 1) {
        float* out = (float*)outv + (size_t)b * oStride;
        const float* rp = res + (size_t)b * oStride;
#pragma unroll
        for (int fi = 0; fi < 4; ++fi) {
            float4 bq = *(const float4*)(bias + m0 + wr * 64 + fi * 16 + lg * 4);
            float bvr[4] = {bq.x, bq.y, bq.z, bq.w};
#pragma unroll
            for (int reg = 0; reg < 4; ++reg) {
                int m = m0 + wr * 64 + fi * 16 + lg * 4 + reg;
                size_t ro = (size_t)m * J + j0 + wc * 64;
#pragma unroll
                for (int fj = 0; fj < 4; ++fj) {
                    size_t idx = ro + fj * 16 + lr;
                    out[idx] = acc[fi][fj][reg] + bvr[reg] + rp[idx];
                }
            }
        }
    } else if (EPI == 3) {
        if (j0 < 1024) {
            short* out = (short*)outv + (size_t)b * oStride;
#pragma unroll
            for (int fi = 0; fi < 4; ++fi)
#pragma unroll
                for (int reg = 0; reg < 4; ++reg) {
                    int m = m0 + wr * 64 + fi * 16 + lg * 4 + reg;
#pragma unroll
                    for (int fj = 0; fj < 4; ++fj)
                        out[(size_t)m * 1024 + j0 + wc * 64 + fj * 16 + lr] = sf(acc[fi][fj][reg]);
                }
        } else {
            short* Vg = (short*)out2v + (size_t)b * o2Stride;
#pragma unroll
            for (int fi = 0; fi < 4; ++fi) {
                int n = m0 + wr * 64 + fi * 16 + lg * 4;
#pragma unroll
                for (int fj = 0; fj < 4; ++fj) {
                    int dg = j0 - 1024 + wc * 64 + fj * 16 + lr;
                    s4v v;
#pragma unroll
                    for (int reg = 0; reg < 4; ++reg) v[reg] = sf(acc[fi][fj][reg]);
                    *(s4v*)(Vg + (size_t)dg * 1024 + n) = v;
                }
            }
        }
    } else {  // EPI == 4
        if (j0 < 512) {
            short* out = (short*)outv + (size_t)b * oStride;
#pragma unroll
            for (int fi = 0; fi < 4; ++fi)
#pragma unroll
                for (int reg = 0; reg < 4; ++reg) {
                    int m = m0 + wr * 64 + fi * 16 + lg * 4 + reg;
                    if (m < M) {
#pragma unroll
                        for (int fj = 0; fj < 4; ++fj)
                            out[(size_t)m * 512 + j0 + wc * 64 + fj * 16 + lr] = sf(acc[fi][fj][reg]);
                    }
                }
        } else {
            short* vt = (short*)out2v + (size_t)b * o2Stride;
#pragma unroll
            for (int fi = 0; fi < 4; ++fi) {
                int l0 = wr * 64 + fi * 16 + lg * 4;      // m0 == 0
                if (l0 < 80) {
#pragma unroll
                    for (int fj = 0; fj < 4; ++fj) {
                        int dg = j0 - 512 + wc * 64 + fj * 16 + lr;
                        s4v v;
#pragma unroll
                        for (int reg = 0; reg < 4; ++reg) v[reg] = sf(acc[fi][fj][reg]);
                        *(s4v*)(vt + (size_t)dg * 80 + l0) = v;
                    }
                }
            }
        }
    }
}

// standard GEMM wrapper
template<int EPI>
__global__ __launch_bounds__(256)
void gemm_std(const short* __restrict__ A, const short* __restrict__ Wt,
              const float* __restrict__ bias, const float* __restrict__ res,
              void* __restrict__ outv, void* __restrict__ out2v,
              int M, int K, int J, long aStride, long wStride, long oStride, long o2Stride)
{
    __shared__ short As[2 * 128 * 40];
    __shared__ short Ws[2 * 128 * 40];
    gemm_body<EPI>(As, Ws, blockIdx.x * 128, blockIdx.y * 128, blockIdx.z,
                   A, Wt, bias, res, outv, out2v, M, K, J,
                   aStride, wStride, oStride, o2Stride);
}

// merged qkv + kv launcher: grid (12, 9, 4). by<8 -> qkv; by==8,bx<8 -> kv
__global__ __launch_bounds__(256)
void gemm_qkv_kv(const short* __restrict__ h1b, const short* __restrict__ qkvwT,
                 short* __restrict__ qkb, short* __restrict__ Vg,
                 const short* __restrict__ ctxb, const short* __restrict__ cakwT,
                 short* __restrict__ k2b, short* __restrict__ v2t)
{
    __shared__ short As[2 * 128 * 40];
    __shared__ short Ws[2 * 128 * 40];
    if (blockIdx.y < 8) {
        gemm_body<3>(As, Ws, blockIdx.x * 128, blockIdx.y * 128, blockIdx.z,
                     h1b, qkvwT, nullptr, nullptr, qkb, Vg,
                     1024, 512, 1536, 524288L, 0L, 1048576L, 524288L);
    } else if (blockIdx.x < 8) {
        gemm_body<4>(As, Ws, blockIdx.x * 128, 0, blockIdx.z,
                     ctxb, cakwT, nullptr, nullptr, k2b, v2t,
                     77, 768, 1024, 59136L, 0L, 39424L, 40960L);
    }
}

// ---------------------------------------------------------------------------
// Fresnel attention v3: swapped QK^T (lane owns one query), in-lane softmax,
// defer-max (thr=8 log2), cvt_pk bf16 pack, setprio around MFMA clusters,
// double-buffered swizzled K/V LDS, one barrier per 64-key tile.
// qkb: [b][n][1024] (q at 0, k at 512); Vg: [b][512][1024] row=h*64+d
// ---------------------------------------------------------------------------
__global__ __launch_bounds__(256)
void fresnel_attn_v3(const short* __restrict__ qkb, const short* __restrict__ Vg,
                     const short* __restrict__ tab, short* __restrict__ ao)
{
    int qb = blockIdx.x, h = blockIdx.y, b = blockIdx.z;
    int n0 = qb * 64;
    __shared__ short Ks[2][64][64];
    __shared__ short Vt[2][64][64];
    __shared__ short Ps[4][16][72];
    __shared__ short tabs[4032];
    int tid = threadIdx.x, w = tid >> 6, lane = tid & 63;
    int lr = lane & 15, lg = lane >> 4;
    const short* qp = qkb + (size_t)b * 1048576;
    const short* vp = Vg + ((size_t)b * 512 + h * 64) * 1024;

    for (int l = tid; l < 504; l += 256)
        *(bf8*)&tabs[l * 8] = *(const bf8*)(tab + l * 8);

    int q = n0 + w * 16 + lr;                 // this lane's query row
    bf8 qf0 = *(const bf8*)(qp + (size_t)q * 1024 + h * 64 + lg * 8);
    bf8 qf1 = *(const bf8*)(qp + (size_t)q * 1024 + h * 64 + 32 + lg * 8);

    // staging: 512 chunks (64 rows x 8), 2 K + 2 V chunks per thread
    int sr0 = tid >> 3, sc0 = tid & 7;
    int sr1 = 32 + sr0;
    int sw0 = ((sc0 ^ (sr0 & 7))) * 8;
    int sw1 = ((sc0 ^ (sr1 & 7))) * 8;

    *(bf8*)&Ks[0][sr0][sw0] = *(const bf8*)(qp + (size_t)sr0 * 1024 + 512 + h * 64 + sc0 * 8);
    *(bf8*)&Ks[0][sr1][sw1] = *(const bf8*)(qp + (size_t)sr1 * 1024 + 512 + h * 64 + sc0 * 8);
    *(bf8*)&Vt[0][sr0][sw0] = *(const bf8*)(vp + (size_t)sr0 * 1024 + sc0 * 8);
    *(bf8*)&Vt[0][sr1][sw1] = *(const bf8*)(vp + (size_t)sr1 * 1024 + sc0 * 8);
    __syncthreads();

    float mrun = -1e30f, lrun = 0.f;          // log2 domain
    f4 o[4];
#pragma unroll
    for (int i = 0; i < 4; ++i) o[i] = zerof4();

    int ybase = (q >> 5) + 31;
    int xbase = (q & 31) + 31 - lg * 4;
    int rsw = lr & 7;
    int rc0 = (lg ^ rsw) * 8;                 // kc=0 swizzled chunk offset
    int rc1 = ((4 + lg) ^ rsw) * 8;           // kc=1

    for (int t = 0; t < 16; ++t) {
        int cur = t & 1;
        int m0 = t << 6;
        bool more = t < 15;
        bf8 nk0, nk1, nv0, nv1;
        if (more) {
            int m1 = m0 + 64;
            nk0 = *(const bf8*)(qp + (size_t)(m1 + sr0) * 1024 + 512 + h * 64 + sc0 * 8);
            nk1 = *(const bf8*)(qp + (size_t)(m1 + sr1) * 1024 + 512 + h * 64 + sc0 * 8);
            nv0 = *(const bf8*)(vp + (size_t)sr0 * 1024 + m1 + sc0 * 8);
            nv1 = *(const bf8*)(vp + (size_t)sr1 * 1024 + m1 + sc0 * 8);
        }

        // QK^T swapped: D[key][query], lane holds query lr, keys fj*16+lg*4+reg
        f4 sa[4];
#pragma unroll
        for (int fj = 0; fj < 4; ++fj) sa[fj] = zerof4();
        __builtin_amdgcn_s_setprio(1);
#pragma unroll
        for (int fj = 0; fj < 4; ++fj)
            sa[fj] = MFMA(*(const bf8*)&Ks[cur][fj * 16 + lr][rc0], qf0, sa[fj]);
#pragma unroll
        for (int fj = 0; fj < 4; ++fj)
            sa[fj] = MFMA(*(const bf8*)&Ks[cur][fj * 16 + lr][rc1], qf1, sa[fj]);
        __builtin_amdgcn_s_setprio(0);

        // scores in log2 domain + interference
        int yb = ybase - (m0 >> 5);
        float pv[4][4];
        float tmax = -1e30f;
#pragma unroll
        for (int fj = 0; fj < 4; ++fj) {
            int rowoff = (yb - (fj >> 1)) * 63 + xbase - (fj & 1) * 16;
#pragma unroll
            for (int reg = 0; reg < 4; ++reg) {
                float t2 = fmaf(sa[fj][reg], 0.18033688011112042f, fs(tabs[rowoff - reg]));
                pv[fj][reg] = t2;
                tmax = fmaxf(tmax, t2);
            }
        }
        // defer-max: only rescale when some lane's local max exceeds mrun+8
        if (__any(tmax > mrun + 8.f)) {
            tmax = fmaxf(tmax, __shfl_xor(tmax, 16));
            tmax = fmaxf(tmax, __shfl_xor(tmax, 32));
            float mnew = fmaxf(mrun, tmax);
            float rsc = EXP2(mrun - mnew);
            mrun = mnew;
            lrun *= rsc;
#pragma unroll
            for (int fd = 0; fd < 4; ++fd)
#pragma unroll
                for (int reg = 0; reg < 4; ++reg) o[fd][reg] *= rsc;
        }
        float psum = 0.f;
#pragma unroll
        for (int fj = 0; fj < 4; ++fj) {
            float p0 = EXP2(pv[fj][0] - mrun);
            float p1 = EXP2(pv[fj][1] - mrun);
            float p2 = EXP2(pv[fj][2] - mrun);
            float p3 = EXP2(pv[fj][3] - mrun);
            psum += (p0 + p1) + (p2 + p3);
            int r01, r23;
            asm("v_cvt_pk_bf16_f32 %0, %1, %2" : "=v"(r01) : "v"(p0), "v"(p1));
            asm("v_cvt_pk_bf16_f32 %0, %1, %2" : "=v"(r23) : "v"(p2), "v"(p3));
            int2 pr; pr.x = r01; pr.y = r23;
            *(int2*)&Ps[w][lr][fj * 16 + lg * 4] = pr;   // row = query lr
        }
        psum += __shfl_xor(psum, 16);
        psum += __shfl_xor(psum, 32);
        lrun += psum;

        // PV: O^T[d][q] = mfma(Vt rows=d, P cols=q)
        bf8 pa0 = *(const bf8*)&Ps[w][lr][lg * 8];
        bf8 pa1 = *(const bf8*)&Ps[w][lr][32 + lg * 8];
        __builtin_amdgcn_s_setprio(1);
#pragma unroll
        for (int fd = 0; fd < 4; ++fd) {
            o[fd] = MFMA(*(const bf8*)&Vt[cur][fd * 16 + lr][rc0], pa0, o[fd]);
            o[fd] = MFMA(*(const bf8*)&Vt[cur][fd * 16 + lr][rc1], pa1, o[fd]);
        }
        __builtin_amdgcn_s_setprio(0);

        if (more) {
            int nb = cur ^ 1;
            *(bf8*)&Ks[nb][sr0][sw0] = nk0;
            *(bf8*)&Ks[nb][sr1][sw1] = nk1;
            *(bf8*)&Vt[nb][sr0][sw0] = nv0;
            *(bf8*)&Vt[nb][sr1][sw1] = nv1;
        }
        __syncthreads();
    }

    float inv = 1.f / lrun;
    size_t rb = ((size_t)b * N_ + q) * 512 + h * 64;
#pragma unroll
    for (int fd = 0; fd < 4; ++fd) {
        s4v ov;
#pragma unroll
        for (int reg = 0; reg < 4; ++reg) ov[reg] = sf(o[fd][reg] * inv);
        *(s4v*)(ao + rb + fd * 16 + lg * 4) = ov;
    }
}

// ---------------------------------------------------------------------------
// Cross attention, bf16 MFMA, single K-tile (L=77 padded to 96).
// q2: [b][1024][512]; k2: [b][77][512]; v2t: [b][512][80] row=h*64+d
// ---------------------------------------------------------------------------
__global__ __launch_bounds__(256)
void cross_attn_mfma(const short* __restrict__ q2, const short* __restrict__ k2,
                     const short* __restrict__ v2t, short* __restrict__ ao2)
{
    int qb = blockIdx.x, h = blockIdx.y, b = blockIdx.z;
    int n0 = qb * 64;
    __shared__ short Qs[64][72], Ks[96][72], Vt[64][104];
    __shared__ short Ps[4][16][104];
    int tid = threadIdx.x, w = tid >> 6, lane = tid & 63;
    int lr = lane & 15, lg = lane >> 4;

    for (int l = tid; l < 512; l += 256) {
        int n = l >> 3, dq = l & 7;
        *(bf8*)&Qs[n][dq * 8] = *(const bf8*)(q2 + ((size_t)b * N_ + n0 + n) * 512 + h * 64 + dq * 8);
    }
    for (int l = tid; l < 768; l += 256) {
        int m = l >> 3, dq = l & 7;
        bf8 v = zero8();
        if (m < L_) v = *(const bf8*)(k2 + ((size_t)b * L_ + m) * 512 + h * 64 + dq * 8);
        *(bf8*)&Ks[m][dq * 8] = v;
    }
    for (int l = tid; l < 768; l += 256) {
        int d = l / 12, cq = l % 12;
        bf8 v = zero8();
        if (cq < 10) v = *(const bf8*)(v2t + ((size_t)b * 512 + h * 64 + d) * 80 + cq * 8);
        *(bf8*)&Vt[d][cq * 8] = v;
    }
    __syncthreads();

    f4 sacc[6];
#pragma unroll
    for (int fj = 0; fj < 6; ++fj) sacc[fj] = zerof4();
    __builtin_amdgcn_s_setprio(1);
#pragma unroll
    for (int kc = 0; kc < 2; ++kc) {
        bf8 aq = *(const bf8*)&Qs[w * 16 + lr][kc * 32 + lg * 8];
#pragma unroll
        for (int fj = 0; fj < 6; ++fj)
            sacc[fj] = MFMA(aq, *(const bf8*)&Ks[fj * 16 + lr][kc * 32 + lg * 8], sacc[fj]);
    }
    __builtin_amdgcn_s_setprio(0);

    float rinv[4];
#pragma unroll
    for (int reg = 0; reg < 4; ++reg) {
        float sv[6];
#pragma unroll
        for (int fj = 0; fj < 6; ++fj) {
            int m = fj * 16 + lr;
            sv[fj] = (m < L_) ? sacc[fj][reg] * 0.125f : -30000.f;
        }
        float mx = sv[0];
#pragma unroll
        for (int fj = 1; fj < 6; ++fj) mx = fmaxf(mx, sv[fj]);
#pragma unroll
        for (int off = 1; off < 16; off <<= 1) mx = fmaxf(mx, __shfl_xor(mx, off));
        float psum = 0.f;
#pragma unroll
        for (int fj = 0; fj < 6; ++fj) {
            float p = __expf(sv[fj] - mx);
            psum += p;
            Ps[w][lg * 4 + reg][fj * 16 + lr] = sf(p);
        }
#pragma unroll
        for (int off = 1; off < 16; off <<= 1) psum += __shfl_xor(psum, off);
        rinv[reg] = 1.f / psum;
    }
    __syncthreads();

    f4 o[4];
#pragma unroll
    for (int fd = 0; fd < 4; ++fd) o[fd] = zerof4();
    __builtin_amdgcn_s_setprio(1);
#pragma unroll
    for (int kc = 0; kc < 3; ++kc) {
        bf8 ap = *(const bf8*)&Ps[w][lr][kc * 32 + lg * 8];
#pragma unroll
        for (int fd = 0; fd < 4; ++fd)
            o[fd] = MFMA(ap, *(const bf8*)&Vt[fd * 16 + lr][kc * 32 + lg * 8], o[fd]);
    }
    __builtin_amdgcn_s_setprio(0);

#pragma unroll
    for (int reg = 0; reg < 4; ++reg) {
        size_t rb = ((size_t)b * N_ + n0 + w * 16 + lg * 4 + reg) * 512 + h * 64;
#pragma unroll
        for (int fd = 0; fd < 4; ++fd)
            ao2[rb + fd * 16 + lr] = sf(o[fd][reg] * rinv[reg]);
    }
}

// ---------------------------------------------------------------------------
extern "C" void kernel_launch(void* const* d_in, const int* in_sizes, int n_in,
                              void* d_out, int out_size, void* d_ws, size_t ws_size,
                              hipStream_t stream)
{
    const float* x    = (const float*)d_in[0];
    const float* ctx  = (const float*)d_in[1];
    const float* gn1w = (const float*)d_in[2];
    const float* gn1b = (const float*)d_in[3];
    const float* gn2w = (const float*)d_in[4];
    const float* gn2b = (const float*)d_in[5];
    const float* qkvw = (const float*)d_in[6];
    const float* faow = (const float*)d_in[7];
    const float* faob = (const float*)d_in[8];
    const float* wl   = (const float*)d_in[9];
    const float* caqw = (const float*)d_in[10];
    const float* cakw = (const float*)d_in[11];
    const float* cavw = (const float*)d_in[12];
    const float* caow = (const float*)d_in[13];
    const float* caob = (const float*)d_in[14];
    float* out = (float*)d_out;
    char* ws = (char*)d_ws;

    float* x1    = (float*)(ws + 0);            // 8 MB fp32 [b][c][n]
    short* qkb   = (short*)(ws + 8388608);      // 8 MB bf16 [b][n][1024] (q|k)
    short* Vg    = (short*)(ws + 16777216);     // 4 MB bf16 [b][512][1024]
    short* h1b   = (short*)(ws + 20971520);     // 4 MB [b][n][512] (h1 / h2)
    short* ao    = (short*)(ws + 25165824);     // 4 MB [b][n][512] (ao / ao2)
    short* q2b   = (short*)(ws + 29360128);     // 4 MB
    short* qkvwT = (short*)(ws + 33554432);     // 1.5 MB  [1536][512]
    short* faowT = (short*)(ws + 35127296);     // 0.5 MB  [512][512]
    short* caqwT = (short*)(ws + 35651584);     // 0.5 MB
    short* cakwT = (short*)(ws + 36175872);     // 0.75 MB [512][768]
    short* cavwT = (short*)(ws + 36962304);     // 0.75 MB (contiguous after cakwT)
    short* caowT = (short*)(ws + 37748736);     // 0.5 MB
    short* k2b   = (short*)(ws + 38273024);     // 308 KB [b][77][512]
    short* v2t   = (short*)(ws + 38588416);     // 320 KB [b][512][80]
    short* ctxb  = (short*)(ws + 38916096);     // 462 KB
    short* tab   = (short*)(ws + 39389184);     // 8 KB

    // L1: gn1 + tab + weight transposes + ctx convert
    prep_mega<<<2679, 256, 0, stream>>>(x, gn1w, gn1b, h1b,
                                        wl, tab, qkvw, qkvwT, faow, faowT,
                                        caqw, caqwT, cakw, cakwT, cavw, cavwT,
                                        caow, caowT, ctx, ctxb);
    // L2: qkv = h1 @ qkv_w (q|k -> qkb, v -> Vg transposed)  +  kv = ctx @ [k|v]
    gemm_qkv_kv<<<dim3(12, 9, 4), 256, 0, stream>>>(
        h1b, qkvwT, qkb, Vg, ctxb, cakwT, k2b, v2t);
    // L3
    fresnel_attn_v3<<<dim3(16, 8, 4), 256, 0, stream>>>(qkb, Vg, tab, ao);
    // L4: x1[c][n] = x[c][n] + (ao @ fa_out_w)^T + fa_out_b[c]
    gemm_std<1><<<dim3(8, 4, 4), 256, 0, stream>>>(
        faowT, ao, faob, x, x1, nullptr, 512, 512, 1024,
        0L, 524288L, 524288L, 0L);
    // L5: h2 = GroupNorm2(x1) -> [n][c] bf16
    gn_kernel<<<dim3(32, 4), 256, 0, stream>>>(x1, gn2w, gn2b, h1b);
    // L6: q2 = h2 @ ca_q_w
    gemm_std<0><<<dim3(4, 8, 4), 256, 0, stream>>>(
        h1b, caqwT, nullptr, nullptr, q2b, nullptr, 1024, 512, 512,
        524288L, 0L, 524288L, 0L);
    // L7
    cross_attn_mfma<<<dim3(16, 8, 4), 256, 0, stream>>>(q2b, k2b, v2t, ao);
    // L8: out[c][n] = x1[c][n] + (ao2 @ ca_out_w)^T + ca_out_b[c]
    gemm_std<1><<<dim3(8, 4, 4), 256, 0, stream>>>(
        caowT, ao, caob, x1, out, nullptr, 512, 512, 1024,
        0L, 524288L, 524288L, 0L);
}

// Round 6
// 201.356 us; speedup vs baseline: 4.8524x; 1.0872x over previous
//
#include <hip/hip_runtime.h>
#include <hip/hip_bf16.h>
#include <math.h>

#define B_    4
#define N_    1024
#define L_    77

typedef float f4 __attribute__((ext_vector_type(4)));
typedef short bf8 __attribute__((ext_vector_type(8)));
typedef short s4v __attribute__((ext_vector_type(4)));

#if __has_builtin(__builtin_amdgcn_exp2f)
#define EXP2(x) __builtin_amdgcn_exp2f(x)
#else
#define EXP2(x) exp2f(x)
#endif

__device__ __forceinline__ float fs(short s) {
    unsigned u = ((unsigned)(unsigned short)s) << 16;
    return __builtin_bit_cast(float, u);
}
__device__ __forceinline__ short sf(float f) {
    unsigned u = __builtin_bit_cast(unsigned, f);
    unsigned r = (u + 0x7FFF + ((u >> 16) & 1)) >> 16;
    return (short)r;
}
__device__ __forceinline__ bf8 zero8() { bf8 v; for (int i = 0; i < 8; ++i) v[i] = 0; return v; }
__device__ __forceinline__ f4 zerof4() { f4 v; for (int i = 0; i < 4; ++i) v[i] = 0.f; return v; }

#define MFMA(a, b, c) __builtin_amdgcn_mfma_f32_16x16x32_bf16((a), (b), (c), 0, 0, 0)

// ---------------------------------------------------------------------------
// Full GroupNorm body (stats + normalize) — used for gn1 inside prep_mega.
// src fp32 [b][512][1024] ([c][n]) -> dst bf16 [b][1024][512] ([n][c]).
// ---------------------------------------------------------------------------
__device__ __forceinline__ void gn_body(const float* __restrict__ src,
                                        const float* __restrict__ w,
                                        const float* __restrict__ bs,
                                        short* __restrict__ dst, int g, int b)
{
    const float* xb = src + ((size_t)b * 512 + g * 16) * 1024;
    float s = 0.f, ss = 0.f;
    for (int l = threadIdx.x; l < 4096; l += 256) {
        float4 v = *(const float4*)(xb + l * 4);
        s += v.x + v.y + v.z + v.w;
        ss += v.x * v.x + v.y * v.y + v.z * v.z + v.w * v.w;
    }
    for (int off = 32; off; off >>= 1) {
        s  += __shfl_down(s,  off);
        ss += __shfl_down(ss, off);
    }
    __shared__ float sred[8], ssred[8];
    int wid = threadIdx.x >> 6;
    if ((threadIdx.x & 63) == 0) { sred[wid] = s; ssred[wid] = ss; }
    __syncthreads();
    if (threadIdx.x == 0) {
        float S = 0.f, SS = 0.f;
        for (int i = 0; i < 4; ++i) { S += sred[i]; SS += ssred[i]; }
        float mu = S * (1.f / 16384.f);
        float var = SS * (1.f / 16384.f) - mu * mu;
        sred[4] = mu; ssred[4] = rsqrtf(var + 1e-5f);
    }
    __syncthreads();
    float mu = sred[4], rs = ssred[4];

    int c4 = threadIdx.x & 3, nb = threadIdx.x >> 2;
    int c = g * 16 + c4 * 4;
    float4 wv = *(const float4*)(w + c);
    float4 bv = *(const float4*)(bs + c);
    for (int rep = 0; rep < 16; ++rep) {
        int n = rep * 64 + nb;
        float v0 = xb[(size_t)(c4 * 4 + 0) * 1024 + n];
        float v1 = xb[(size_t)(c4 * 4 + 1) * 1024 + n];
        float v2 = xb[(size_t)(c4 * 4 + 2) * 1024 + n];
        float v3 = xb[(size_t)(c4 * 4 + 3) * 1024 + n];
        s4v hb;
        hb[0] = sf((v0 - mu) * rs * wv.x + bv.x);
        hb[1] = sf((v1 - mu) * rs * wv.y + bv.y);
        hb[2] = sf((v2 - mu) * rs * wv.z + bv.z);
        hb[3] = sf((v3 - mu) * rs * wv.w + bv.w);
        *(s4v*)(dst + ((size_t)b * 1024 + n) * 512 + c) = hb;
    }
}

// ---------------------------------------------------------------------------
// prep mega-kernel: gn1 + tab (log2e-scaled) + gstat zero + 6 weight
// transposes + ctx->bf16.
// ---------------------------------------------------------------------------
__device__ __forceinline__ void wtile(const float* __restrict__ in, short* __restrict__ out,
                                      int K, int J, int tile, int tid, float (*t)[33])
{
    int jt = J >> 5;
    int j0 = (tile % jt) * 32, k0 = (tile / jt) * 32;
    int tx = tid & 31, ty = tid >> 5;
#pragma unroll
    for (int i = 0; i < 4; ++i)
        t[ty + i * 8][tx] = in[(size_t)(k0 + ty + i * 8) * J + j0 + tx];
    __syncthreads();
#pragma unroll
    for (int i = 0; i < 4; ++i)
        out[(size_t)(j0 + ty + i * 8) * K + k0 + tx] = sf(t[tx][ty + i * 8]);
}

__global__ __launch_bounds__(256)
void prep_mega(const float* __restrict__ x, const float* __restrict__ gn1w,
               const float* __restrict__ gn1b, short* __restrict__ h1b,
               const float* __restrict__ wl, short* __restrict__ tab,
               float* __restrict__ gstat,
               const float* __restrict__ qkvw, short* __restrict__ qkvwT,
               const float* __restrict__ faow, short* __restrict__ faowT,
               const float* __restrict__ caqw, short* __restrict__ caqwT,
               const float* __restrict__ cakw, short* __restrict__ cakwT,
               const float* __restrict__ cavw, short* __restrict__ cavwT,
               const float* __restrict__ caow, short* __restrict__ caowT,
               const float* __restrict__ ctx, short* __restrict__ ctxb)
{
    __shared__ float tls[32][33];
    int bid = blockIdx.x, tid = threadIdx.x;
    if (bid < 128) { gn_body(x, gn1w, gn1b, h1b, bid & 31, bid >> 5); return; }
    bid -= 128;
    if (bid < 16) {
        if (bid == 0) gstat[tid] = 0.f;       // 256 floats = 4 b x 32 g x 2
        int idx = bid * 256 + tid;
        if (idx < 3969) {
            int i = idx / 63, j = idx - i * 63;
            float dy = (float)(i - 31), dx = (float)(j - 31);
            float dist = sqrtf(dy * dy + dx * dx + 1e-8f);
            float den = fabsf(wl[0]) * 32.0f + 1e-6f;
            tab[idx] = sf(0.1f * cosf(6.283185307179586f * dist / den) * 1.4426950408889634f);
        }
        return;
    }
    bid -= 16;
    if (bid < 768) { wtile(qkvw, qkvwT, 512, 1536, bid, tid, tls); return; }
    bid -= 768;
    if (bid < 256) { wtile(faow, faowT, 512, 512, bid, tid, tls); return; }
    bid -= 256;
    if (bid < 256) { wtile(caqw, caqwT, 512, 512, bid, tid, tls); return; }
    bid -= 256;
    if (bid < 384) { wtile(cakw, cakwT, 768, 512, bid, tid, tls); return; }
    bid -= 384;
    if (bid < 384) { wtile(cavw, cavwT, 768, 512, bid, tid, tls); return; }
    bid -= 384;
    if (bid < 256) { wtile(caow, caowT, 512, 512, bid, tid, tls); return; }
    bid -= 256;
    int base = bid * 1024 + tid * 4;
    float4 v = *(const float4*)(ctx + base);
    s4v o; o[0] = sf(v.x); o[1] = sf(v.y); o[2] = sf(v.z); o[3] = sf(v.w);
    *(s4v*)(ctxb + base) = o;
}

// ---------------------------------------------------------------------------
// gn2 normalize-only: stats precomputed in fa_out GEMM epilogue (gstat).
// ---------------------------------------------------------------------------
__global__ __launch_bounds__(256)
void gn2_norm(const float* __restrict__ x1, const float* __restrict__ gstat,
              const float* __restrict__ w, const float* __restrict__ bs,
              short* __restrict__ dst)
{
    int g = blockIdx.x, b = blockIdx.y;
    float S  = gstat[b * 64 + g * 2];
    float SS = gstat[b * 64 + g * 2 + 1];
    float mu = S * (1.f / 16384.f);
    float var = SS * (1.f / 16384.f) - mu * mu;
    float rs = rsqrtf(var + 1e-5f);
    const float* xb = x1 + ((size_t)b * 512 + g * 16) * 1024;

    int c4 = threadIdx.x & 3, nb = threadIdx.x >> 2;
    int c = g * 16 + c4 * 4;
    float4 wv = *(const float4*)(w + c);
    float4 bv = *(const float4*)(bs + c);
    for (int rep = 0; rep < 16; ++rep) {
        int n = rep * 64 + nb;
        float v0 = xb[(size_t)(c4 * 4 + 0) * 1024 + n];
        float v1 = xb[(size_t)(c4 * 4 + 1) * 1024 + n];
        float v2 = xb[(size_t)(c4 * 4 + 2) * 1024 + n];
        float v3 = xb[(size_t)(c4 * 4 + 3) * 1024 + n];
        s4v hb;
        hb[0] = sf((v0 - mu) * rs * wv.x + bv.x);
        hb[1] = sf((v1 - mu) * rs * wv.y + bv.y);
        hb[2] = sf((v2 - mu) * rs * wv.z + bv.z);
        hb[3] = sf((v3 - mu) * rs * wv.w + bv.w);
        *(s4v*)(dst + ((size_t)b * 1024 + n) * 512 + c) = hb;
    }
}

// ---------------------------------------------------------------------------
// MFMA GEMM body, 64x128 tile, 4 waves (2x2 of 32x64), dbuf LDS, one barrier
// per K-step. out[b][m][j] = sum_k A[b][m][k] * Wt[b][j][k]
// EPI 1: fp32 store + bias[m] + res   EPI 2: EPI1 + group-stat atomics
// EPI 3: qkv (q|k store / V transpose)  EPI 4: kv (k store / v2t transpose)
// As: 2*64*40 shorts, Ws: 2*128*40 shorts.
// ---------------------------------------------------------------------------
template<int EPI>
__device__ __forceinline__ void gemm_body(
    short* As, short* Ws, int j0, int m0, int b,
    const short* __restrict__ A, const short* __restrict__ Wt,
    const float* __restrict__ bias, const float* __restrict__ res,
    void* __restrict__ outv, void* __restrict__ out2v, float* __restrict__ gstat,
    int M, int K, int J, long aStride, long wStride, long oStride, long o2Stride)
{
    int tid = threadIdx.x, w = tid >> 6, lane = tid & 63;
    int lr = lane & 15, lg = lane >> 4;
    int wr = w >> 1, wc = w & 1;
    const short* Ab  = A  + (size_t)b * aStride;
    const short* Wtb = Wt + (size_t)b * wStride;
    int r0 = tid >> 2, c0 = (tid & 3) * 8;
    bool gA0 = (m0 + r0) < M;
    const short* ap0 = Ab + (size_t)(m0 + r0) * K + c0;
    const short* wp0 = Wtb + (size_t)(j0 + r0) * K + c0;
    const short* wp1 = Wtb + (size_t)(j0 + 64 + r0) * K + c0;

    f4 acc[2][4];
#pragma unroll
    for (int i = 0; i < 2; ++i)
#pragma unroll
        for (int j = 0; j < 4; ++j) acc[i][j] = zerof4();

    *(bf8*)(As + r0 * 40 + c0) = gA0 ? *(const bf8*)ap0 : zero8();
    *(bf8*)(Ws + r0 * 40 + c0) = *(const bf8*)wp0;
    *(bf8*)(Ws + (64 + r0) * 40 + c0) = *(const bf8*)wp1;
    __syncthreads();

    int nk = K >> 5;
    for (int t = 0; t < nk; ++t) {
        int curA = (t & 1) * 2560, curW = (t & 1) * 5120;
        bool more = (t + 1) < nk;
        bf8 na0, nw0, nw1;
        if (more) {
            int ko = (t + 1) << 5;
            na0 = gA0 ? *(const bf8*)(ap0 + ko) : zero8();
            nw0 = *(const bf8*)(wp0 + ko);
            nw1 = *(const bf8*)(wp1 + ko);
        }
        bf8 af[2], bfr[4];
#pragma unroll
        for (int fi = 0; fi < 2; ++fi)
            af[fi] = *(const bf8*)(As + curA + (wr * 32 + fi * 16 + lr) * 40 + lg * 8);
#pragma unroll
        for (int fj = 0; fj < 4; ++fj)
            bfr[fj] = *(const bf8*)(Ws + curW + (wc * 64 + fj * 16 + lr) * 40 + lg * 8);
#pragma unroll
        for (int fi = 0; fi < 2; ++fi)
#pragma unroll
            for (int fj = 0; fj < 4; ++fj)
                acc[fi][fj] = MFMA(af[fi], bfr[fj], acc[fi][fj]);
        if (more) {
            int nbA = 2560 - curA, nbW = 5120 - curW;
            *(bf8*)(As + nbA + r0 * 40 + c0) = na0;
            *(bf8*)(Ws + nbW + r0 * 40 + c0) = nw0;
            *(bf8*)(Ws + nbW + (64 + r0) * 40 + c0) = nw1;
        }
        __syncthreads();
    }

    if (EPI == 1 || EPI == 2) {
        float* out = (float*)outv + (size_t)b * oStride;
        const float* rp = res + (size_t)b * oStride;
#pragma unroll
        for (int fi = 0; fi < 2; ++fi) {
            int mbase = m0 + wr * 32 + fi * 16 + lg * 4;
            float4 bq = *(const float4*)(bias + mbase);
            float bvr[4] = {bq.x, bq.y, bq.z, bq.w};
            float sg = 0.f, ssg = 0.f;
#pragma unroll
            for (int reg = 0; reg < 4; ++reg) {
                size_t ro = (size_t)(mbase + reg) * J + j0 + wc * 64;
#pragma unroll
                for (int fj = 0; fj < 4; ++fj) {
                    size_t idx = ro + fj * 16 + lr;
                    float v = acc[fi][fj][reg] + bvr[reg] + rp[idx];
                    out[idx] = v;
                    if (EPI == 2) { sg += v; ssg += v * v; }
                }
            }
            if (EPI == 2) {
#pragma unroll
                for (int off = 32; off; off >>= 1) {
                    sg  += __shfl_down(sg,  off);
                    ssg += __shfl_down(ssg, off);
                }
                if (lane == 0) {
                    int g = mbase >> 4;
                    atomicAdd(&gstat[b * 64 + g * 2], sg);
                    atomicAdd(&gstat[b * 64 + g * 2 + 1], ssg);
                }
            }
        }
    } else if (EPI == 3) {
        if (j0 < 1024) {
            short* out = (short*)outv + (size_t)b * oStride;
#pragma unroll
            for (int fi = 0; fi < 2; ++fi)
#pragma unroll
                for (int reg = 0; reg < 4; ++reg) {
                    int m = m0 + wr * 32 + fi * 16 + lg * 4 + reg;
#pragma unroll
                    for (int fj = 0; fj < 4; ++fj)
                        out[(size_t)m * 1024 + j0 + wc * 64 + fj * 16 + lr] = sf(acc[fi][fj][reg]);
                }
        } else {
            short* Vgp = (short*)out2v + (size_t)b * o2Stride;
#pragma unroll
            for (int fi = 0; fi < 2; ++fi) {
                int n = m0 + wr * 32 + fi * 16 + lg * 4;
#pragma unroll
                for (int fj = 0; fj < 4; ++fj) {
                    int dg = j0 - 1024 + wc * 64 + fj * 16 + lr;
                    s4v v;
#pragma unroll
                    for (int reg = 0; reg < 4; ++reg) v[reg] = sf(acc[fi][fj][reg]);
                    *(s4v*)(Vgp + (size_t)dg * 1024 + n) = v;
                }
            }
        }
    } else {  // EPI == 4
        if (j0 < 512) {
            short* out = (short*)outv + (size_t)b * oStride;
#pragma unroll
            for (int fi = 0; fi < 2; ++fi)
#pragma unroll
                for (int reg = 0; reg < 4; ++reg) {
                    int m = m0 + wr * 32 + fi * 16 + lg * 4 + reg;
                    if (m < M) {
#pragma unroll
                        for (int fj = 0; fj < 4; ++fj)
                            out[(size_t)m * 512 + j0 + wc * 64 + fj * 16 + lr] = sf(acc[fi][fj][reg]);
                    }
                }
        } else {
            short* vt = (short*)out2v + (size_t)b * o2Stride;
#pragma unroll
            for (int fi = 0; fi < 2; ++fi) {
                int l0 = m0 + wr * 32 + fi * 16 + lg * 4;
                if (l0 < 80) {
#pragma unroll
                    for (int fj = 0; fj < 4; ++fj) {
                        int dg = j0 - 512 + wc * 64 + fj * 16 + lr;
                        s4v v;
#pragma unroll
                        for (int reg = 0; reg < 4; ++reg) v[reg] = sf(acc[fi][fj][reg]);
                        *(s4v*)(vt + (size_t)dg * 80 + l0) = v;
                    }
                }
            }
        }
    }
}

template<int EPI>
__global__ __launch_bounds__(256)
void gemm_std(const short* __restrict__ A, const short* __restrict__ Wt,
              const float* __restrict__ bias, const float* __restrict__ res,
              void* __restrict__ outv, void* __restrict__ out2v, float* __restrict__ gstat,
              int M, int K, int J, long aStride, long wStride, long oStride, long o2Stride)
{
    __shared__ short As[2 * 64 * 40];
    __shared__ short Ws[2 * 128 * 40];
    gemm_body<EPI>(As, Ws, blockIdx.x * 128, blockIdx.y * 64, blockIdx.z,
                   A, Wt, bias, res, outv, out2v, gstat, M, K, J,
                   aStride, wStride, oStride, o2Stride);
}

// merged qkv + kv launcher: grid (12, 18, 4). by<16 -> qkv; by>=16,bx<8 -> kv
__global__ __launch_bounds__(256)
void gemm_qkv_kv(const short* __restrict__ h1b, const short* __restrict__ qkvwT,
                 short* __restrict__ qkb, short* __restrict__ Vg,
                 const short* __restrict__ ctxb, const short* __restrict__ cakwT,
                 short* __restrict__ k2b, short* __restrict__ v2t)
{
    __shared__ short As[2 * 64 * 40];
    __shared__ short Ws[2 * 128 * 40];
    if (blockIdx.y < 16) {
        gemm_body<3>(As, Ws, blockIdx.x * 128, blockIdx.y * 64, blockIdx.z,
                     h1b, qkvwT, nullptr, nullptr, qkb, Vg, nullptr,
                     1024, 512, 1536, 524288L, 0L, 1048576L, 524288L);
    } else if (blockIdx.x < 8) {
        gemm_body<4>(As, Ws, blockIdx.x * 128, (blockIdx.y - 16) * 64, blockIdx.z,
                     ctxb, cakwT, nullptr, nullptr, k2b, v2t, nullptr,
                     77, 768, 1024, 59136L, 0L, 39424L, 40960L);
    }
}

// ---------------------------------------------------------------------------
// Fresnel attention v3 (unchanged from round 4).
// ---------------------------------------------------------------------------
__global__ __launch_bounds__(256)
void fresnel_attn_v3(const short* __restrict__ qkb, const short* __restrict__ Vg,
                     const short* __restrict__ tab, short* __restrict__ ao)
{
    int qb = blockIdx.x, h = blockIdx.y, b = blockIdx.z;
    int n0 = qb * 64;
    __shared__ short Ks[2][64][64];
    __shared__ short Vt[2][64][64];
    __shared__ short Ps[4][16][72];
    __shared__ short tabs[4032];
    int tid = threadIdx.x, w = tid >> 6, lane = tid & 63;
    int lr = lane & 15, lg = lane >> 4;
    const short* qp = qkb + (size_t)b * 1048576;
    const short* vp = Vg + ((size_t)b * 512 + h * 64) * 1024;

    for (int l = tid; l < 504; l += 256)
        *(bf8*)&tabs[l * 8] = *(const bf8*)(tab + l * 8);

    int q = n0 + w * 16 + lr;
    bf8 qf0 = *(const bf8*)(qp + (size_t)q * 1024 + h * 64 + lg * 8);
    bf8 qf1 = *(const bf8*)(qp + (size_t)q * 1024 + h * 64 + 32 + lg * 8);

    int sr0 = tid >> 3, sc0 = tid & 7;
    int sr1 = 32 + sr0;
    int sw0 = ((sc0 ^ (sr0 & 7))) * 8;
    int sw1 = ((sc0 ^ (sr1 & 7))) * 8;

    *(bf8*)&Ks[0][sr0][sw0] = *(const bf8*)(qp + (size_t)sr0 * 1024 + 512 + h * 64 + sc0 * 8);
    *(bf8*)&Ks[0][sr1][sw1] = *(const bf8*)(qp + (size_t)sr1 * 1024 + 512 + h * 64 + sc0 * 8);
    *(bf8*)&Vt[0][sr0][sw0] = *(const bf8*)(vp + (size_t)sr0 * 1024 + sc0 * 8);
    *(bf8*)&Vt[0][sr1][sw1] = *(const bf8*)(vp + (size_t)sr1 * 1024 + sc0 * 8);
    __syncthreads();

    float mrun = -1e30f, lrun = 0.f;
    f4 o[4];
#pragma unroll
    for (int i = 0; i < 4; ++i) o[i] = zerof4();

    int ybase = (q >> 5) + 31;
    int xbase = (q & 31) + 31 - lg * 4;
    int rsw = lr & 7;
    int rc0 = (lg ^ rsw) * 8;
    int rc1 = ((4 + lg) ^ rsw) * 8;

    for (int t = 0; t < 16; ++t) {
        int cur = t & 1;
        int m0 = t << 6;
        bool more = t < 15;
        bf8 nk0, nk1, nv0, nv1;
        if (more) {
            int m1 = m0 + 64;
            nk0 = *(const bf8*)(qp + (size_t)(m1 + sr0) * 1024 + 512 + h * 64 + sc0 * 8);
            nk1 = *(const bf8*)(qp + (size_t)(m1 + sr1) * 1024 + 512 + h * 64 + sc0 * 8);
            nv0 = *(const bf8*)(vp + (size_t)sr0 * 1024 + m1 + sc0 * 8);
            nv1 = *(const bf8*)(vp + (size_t)sr1 * 1024 + m1 + sc0 * 8);
        }

        f4 sa[4];
#pragma unroll
        for (int fj = 0; fj < 4; ++fj) sa[fj] = zerof4();
        __builtin_amdgcn_s_setprio(1);
#pragma unroll
        for (int fj = 0; fj < 4; ++fj)
            sa[fj] = MFMA(*(const bf8*)&Ks[cur][fj * 16 + lr][rc0], qf0, sa[fj]);
#pragma unroll
        for (int fj = 0; fj < 4; ++fj)
            sa[fj] = MFMA(*(const bf8*)&Ks[cur][fj * 16 + lr][rc1], qf1, sa[fj]);
        __builtin_amdgcn_s_setprio(0);

        int yb = ybase - (m0 >> 5);
        float pv[4][4];
        float tmax = -1e30f;
#pragma unroll
        for (int fj = 0; fj < 4; ++fj) {
            int rowoff = (yb - (fj >> 1)) * 63 + xbase - (fj & 1) * 16;
#pragma unroll
            for (int reg = 0; reg < 4; ++reg) {
                float t2 = fmaf(sa[fj][reg], 0.18033688011112042f, fs(tabs[rowoff - reg]));
                pv[fj][reg] = t2;
                tmax = fmaxf(tmax, t2);
            }
        }
        if (__any(tmax > mrun + 8.f)) {
            tmax = fmaxf(tmax, __shfl_xor(tmax, 16));
            tmax = fmaxf(tmax, __shfl_xor(tmax, 32));
            float mnew = fmaxf(mrun, tmax);
            float rsc = EXP2(mrun - mnew);
            mrun = mnew;
            lrun *= rsc;
#pragma unroll
            for (int fd = 0; fd < 4; ++fd)
#pragma unroll
                for (int reg = 0; reg < 4; ++reg) o[fd][reg] *= rsc;
        }
        float psum = 0.f;
#pragma unroll
        for (int fj = 0; fj < 4; ++fj) {
            float p0 = EXP2(pv[fj][0] - mrun);
            float p1 = EXP2(pv[fj][1] - mrun);
            float p2 = EXP2(pv[fj][2] - mrun);
            float p3 = EXP2(pv[fj][3] - mrun);
            psum += (p0 + p1) + (p2 + p3);
            int r01, r23;
            asm("v_cvt_pk_bf16_f32 %0, %1, %2" : "=v"(r01) : "v"(p0), "v"(p1));
            asm("v_cvt_pk_bf16_f32 %0, %1, %2" : "=v"(r23) : "v"(p2), "v"(p3));
            int2 pr; pr.x = r01; pr.y = r23;
            *(int2*)&Ps[w][lr][fj * 16 + lg * 4] = pr;
        }
        psum += __shfl_xor(psum, 16);
        psum += __shfl_xor(psum, 32);
        lrun += psum;

        bf8 pa0 = *(const bf8*)&Ps[w][lr][lg * 8];
        bf8 pa1 = *(const bf8*)&Ps[w][lr][32 + lg * 8];
        __builtin_amdgcn_s_setprio(1);
#pragma unroll
        for (int fd = 0; fd < 4; ++fd) {
            o[fd] = MFMA(*(const bf8*)&Vt[cur][fd * 16 + lr][rc0], pa0, o[fd]);
            o[fd] = MFMA(*(const bf8*)&Vt[cur][fd * 16 + lr][rc1], pa1, o[fd]);
        }
        __builtin_amdgcn_s_setprio(0);

        if (more) {
            int nb = cur ^ 1;
            *(bf8*)&Ks[nb][sr0][sw0] = nk0;
            *(bf8*)&Ks[nb][sr1][sw1] = nk1;
            *(bf8*)&Vt[nb][sr0][sw0] = nv0;
            *(bf8*)&Vt[nb][sr1][sw1] = nv1;
        }
        __syncthreads();
    }

    float inv = 1.f / lrun;
    size_t rb = ((size_t)b * N_ + q) * 512 + h * 64;
#pragma unroll
    for (int fd = 0; fd < 4; ++fd) {
        s4v ov;
#pragma unroll
        for (int reg = 0; reg < 4; ++reg) ov[reg] = sf(o[fd][reg] * inv);
        *(s4v*)(ao + rb + fd * 16 + lg * 4) = ov;
    }
}

// ---------------------------------------------------------------------------
// Cross attention with fused q-projection.
// h2: [b][1024][512] bf16; qwT: caqwT [512][512]; k2: [b][77][512];
// v2t: [b][512][80]; out ao2 [b][1024][512].
// q-tile = h2[n0:n0+64] @ qwT[h*64:h*64+64]^T via 16-step mini-GEMM.
// ---------------------------------------------------------------------------
__global__ __launch_bounds__(256)
void cross_attn_fused(const short* __restrict__ h2, const short* __restrict__ qwT,
                      const short* __restrict__ k2, const short* __restrict__ v2t,
                      short* __restrict__ ao2)
{
    int qb = blockIdx.x, h = blockIdx.y, b = blockIdx.z;
    int n0 = qb * 64;
    __shared__ short hq[2][64][40], wq[2][64][40];
    __shared__ short Qs[64][72], Ks[96][72], Vt[64][104];
    __shared__ short Ps[4][16][104];
    int tid = threadIdx.x, w = tid >> 6, lane = tid & 63;
    int lr = lane & 15, lg = lane >> 4;

    // stage K and V (used after q-proj; first barrier below covers them)
    for (int l = tid; l < 768; l += 256) {
        int m = l >> 3, dq = l & 7;
        bf8 v = zero8();
        if (m < L_) v = *(const bf8*)(k2 + ((size_t)b * L_ + m) * 512 + h * 64 + dq * 8);
        *(bf8*)&Ks[m][dq * 8] = v;
    }
    for (int l = tid; l < 768; l += 256) {
        int d = l / 12, cq = l % 12;
        bf8 v = zero8();
        if (cq < 10) v = *(const bf8*)(v2t + ((size_t)b * 512 + h * 64 + d) * 80 + cq * 8);
        *(bf8*)&Vt[d][cq * 8] = v;
    }

    // q-projection mini-GEMM: M=64 n-rows, J=64 d-cols, K=512
    int r0 = tid >> 2, c0 = (tid & 3) * 8;
    const short* hp = h2 + ((size_t)b * 1024 + n0 + r0) * 512 + c0;
    const short* wp = qwT + (size_t)(h * 64 + r0) * 512 + c0;
    *(bf8*)&hq[0][r0][c0] = *(const bf8*)hp;
    *(bf8*)&wq[0][r0][c0] = *(const bf8*)wp;
    __syncthreads();

    f4 qacc[4];
#pragma unroll
    for (int j = 0; j < 4; ++j) qacc[j] = zerof4();
    for (int t = 0; t < 16; ++t) {
        int cur = t & 1;
        bool more = t < 15;
        bf8 nh, nw;
        if (more) {
            int ko = (t + 1) << 5;
            nh = *(const bf8*)(hp + ko);
            nw = *(const bf8*)(wp + ko);
        }
        bf8 af = *(const bf8*)&hq[cur][w * 16 + lr][lg * 8];
#pragma unroll
        for (int fj = 0; fj < 4; ++fj)
            qacc[fj] = MFMA(af, *(const bf8*)&wq[cur][fj * 16 + lr][lg * 8], qacc[fj]);
        if (more) {
            int nb = cur ^ 1;
            *(bf8*)&hq[nb][r0][c0] = nh;
            *(bf8*)&wq[nb][r0][c0] = nw;
        }
        __syncthreads();
    }
    // write q-tile to Qs: n = w*16+lg*4+reg, d = fj*16+lr
#pragma unroll
    for (int fj = 0; fj < 4; ++fj)
#pragma unroll
        for (int reg = 0; reg < 4; ++reg)
            Qs[w * 16 + lg * 4 + reg][fj * 16 + lr] = sf(qacc[fj][reg]);
    __syncthreads();

    f4 sacc[6];
#pragma unroll
    for (int fj = 0; fj < 6; ++fj) sacc[fj] = zerof4();
    __builtin_amdgcn_s_setprio(1);
#pragma unroll
    for (int kc = 0; kc < 2; ++kc) {
        bf8 aq = *(const bf8*)&Qs[w * 16 + lr][kc * 32 + lg * 8];
#pragma unroll
        for (int fj = 0; fj < 6; ++fj)
            sacc[fj] = MFMA(aq, *(const bf8*)&Ks[fj * 16 + lr][kc * 32 + lg * 8], sacc[fj]);
    }
    __builtin_amdgcn_s_setprio(0);

    float rinv[4];
#pragma unroll
    for (int reg = 0; reg < 4; ++reg) {
        float sv[6];
#pragma unroll
        for (int fj = 0; fj < 6; ++fj) {
            int m = fj * 16 + lr;
            sv[fj] = (m < L_) ? sacc[fj][reg] * 0.125f : -30000.f;
        }
        float mx = sv[0];
#pragma unroll
        for (int fj = 1; fj < 6; ++fj) mx = fmaxf(mx, sv[fj]);
#pragma unroll
        for (int off = 1; off < 16; off <<= 1) mx = fmaxf(mx, __shfl_xor(mx, off));
        float psum = 0.f;
#pragma unroll
        for (int fj = 0; fj < 6; ++fj) {
            float p = __expf(sv[fj] - mx);
            psum += p;
            Ps[w][lg * 4 + reg][fj * 16 + lr] = sf(p);
        }
#pragma unroll
        for (int off = 1; off < 16; off <<= 1) psum += __shfl_xor(psum, off);
        rinv[reg] = 1.f / psum;
    }
    __syncthreads();

    f4 o[4];
#pragma unroll
    for (int fd = 0; fd < 4; ++fd) o[fd] = zerof4();
    __builtin_amdgcn_s_setprio(1);
#pragma unroll
    for (int kc = 0; kc < 3; ++kc) {
        bf8 ap = *(const bf8*)&Ps[w][lr][kc * 32 + lg * 8];
#pragma unroll
        for (int fd = 0; fd < 4; ++fd)
            o[fd] = MFMA(ap, *(const bf8*)&Vt[fd * 16 + lr][kc * 32 + lg * 8], o[fd]);
    }
    __builtin_amdgcn_s_setprio(0);

#pragma unroll
    for (int reg = 0; reg < 4; ++reg) {
        size_t rb = ((size_t)b * N_ + n0 + w * 16 + lg * 4 + reg) * 512 + h * 64;
#pragma unroll
        for (int fd = 0; fd < 4; ++fd)
            ao2[rb + fd * 16 + lr] = sf(o[fd][reg] * rinv[reg]);
    }
}

// ---------------------------------------------------------------------------
extern "C" void kernel_launch(void* const* d_in, const int* in_sizes, int n_in,
                              void* d_out, int out_size, void* d_ws, size_t ws_size,
                              hipStream_t stream)
{
    const float* x    = (const float*)d_in[0];
    const float* ctx  = (const float*)d_in[1];
    const float* gn1w = (const float*)d_in[2];
    const float* gn1b = (const float*)d_in[3];
    const float* gn2w = (const float*)d_in[4];
    const float* gn2b = (const float*)d_in[5];
    const float* qkvw = (const float*)d_in[6];
    const float* faow = (const float*)d_in[7];
    const float* faob = (const float*)d_in[8];
    const float* wl   = (const float*)d_in[9];
    const float* caqw = (const float*)d_in[10];
    const float* cakw = (const float*)d_in[11];
    const float* cavw = (const float*)d_in[12];
    const float* caow = (const float*)d_in[13];
    const float* caob = (const float*)d_in[14];
    float* out = (float*)d_out;
    char* ws = (char*)d_ws;

    float* x1    = (float*)(ws + 0);            // 8 MB fp32 [b][c][n]
    short* qkb   = (short*)(ws + 8388608);      // 8 MB bf16 [b][n][1024] (q|k)
    short* Vg    = (short*)(ws + 16777216);     // 4 MB bf16 [b][512][1024]
    short* h1b   = (short*)(ws + 20971520);     // 4 MB [b][n][512] (h1 / h2)
    short* ao    = (short*)(ws + 25165824);     // 4 MB [b][n][512] (ao / ao2)
    float* gstat = (float*)(ws + 29360128);     // 1 KB (4 b x 32 g x 2)
    short* qkvwT = (short*)(ws + 33554432);     // 1.5 MB  [1536][512]
    short* faowT = (short*)(ws + 35127296);     // 0.5 MB  [512][512]
    short* caqwT = (short*)(ws + 35651584);     // 0.5 MB
    short* cakwT = (short*)(ws + 36175872);     // 0.75 MB [512][768]
    short* cavwT = (short*)(ws + 36962304);     // 0.75 MB (contiguous after cakwT)
    short* caowT = (short*)(ws + 37748736);     // 0.5 MB
    short* k2b   = (short*)(ws + 38273024);     // 308 KB [b][77][512]
    short* v2t   = (short*)(ws + 38588416);     // 320 KB [b][512][80]
    short* ctxb  = (short*)(ws + 38916096);     // 462 KB
    short* tab   = (short*)(ws + 39389184);     // 8 KB

    // L1: gn1 + tab + gstat zero + weight transposes + ctx convert
    prep_mega<<<2679, 256, 0, stream>>>(x, gn1w, gn1b, h1b,
                                        wl, tab, gstat, qkvw, qkvwT, faow, faowT,
                                        caqw, caqwT, cakw, cakwT, cavw, cavwT,
                                        caow, caowT, ctx, ctxb);
    // L2: qkv (q|k -> qkb, v -> Vg transposed) + kv (k -> k2b, v -> v2t)
    gemm_qkv_kv<<<dim3(12, 18, 4), 256, 0, stream>>>(
        h1b, qkvwT, qkb, Vg, ctxb, cakwT, k2b, v2t);
    // L3
    fresnel_attn_v3<<<dim3(16, 8, 4), 256, 0, stream>>>(qkb, Vg, tab, ao);
    // L4: x1[c][n] = x + (ao @ fa_out_w)^T + b  (+ group-stat atomics)
    gemm_std<2><<<dim3(8, 8, 4), 256, 0, stream>>>(
        faowT, ao, faob, x, x1, nullptr, gstat, 512, 512, 1024,
        0L, 524288L, 524288L, 0L);
    // L5: h2 = normalize(x1) using precomputed stats
    gn2_norm<<<dim3(32, 4), 256, 0, stream>>>(x1, gstat, gn2w, gn2b, h1b);
    // L6: cross attention with fused q-projection
    cross_attn_fused<<<dim3(16, 8, 4), 256, 0, stream>>>(h1b, caqwT, k2b, v2t, ao);
    // L7: out[c][n] = x1 + (ao2 @ ca_out_w)^T + b
    gemm_std<1><<<dim3(8, 8, 4), 256, 0, stream>>>(
        caowT, ao, caob, x1, out, nullptr, nullptr, 512, 512, 1024,
        0L, 524288L, 524288L, 0L);
}